// Round 8
// baseline (9005.188 us; speedup 1.0000x reference)
//
#include <hip/hip_runtime.h>
#include <math.h>

#define NR 8192      // NA == NT
#define DIM 256
#define NBLK 256     // fused-kernel blocks == column-partial chunks (1 per CU)
#define CROWS 32     // rows per chunk
#define RSC 2        // rows per sub-chunk
#define NSUB 16      // sub-chunks per chunk
// 10 * log2(e): converts distances directly into base-2 log domain
#define SCALE2 14.426950408889634f

// v_exp_f32 / v_log_f32 are base-2 natively — use them raw
__device__ __forceinline__ float fexp2(float x) {
#if __has_builtin(__builtin_amdgcn_exp2f)
    return __builtin_amdgcn_exp2f(x);
#else
    return exp2f(x);
#endif
}
__device__ __forceinline__ float flog2(float x) {
#if __has_builtin(__builtin_amdgcn_logf)
    return __builtin_amdgcn_logf(x);
#else
    return log2f(x);
#endif
}

// base-2 online LSE combine
__device__ __forceinline__ void lse_comb2(float& m, float& s, float mo, float so) {
    float nm = fmaxf(m, mo);
    s = s * fexp2(m - nm) + so * fexp2(mo - nm);
    m = nm;
}

// grouped-4 online LSE update
__device__ __forceinline__ void lse_upd4(float& m, float& s,
                                         float v0, float v1, float v2, float v3) {
    float m4 = fmaxf(fmaxf(v0, v1), fmaxf(v2, v3));
    float nm = fmaxf(m, m4);
    float e = fexp2(v0 - nm) + fexp2(v1 - nm) + fexp2(v2 - nm) + fexp2(v3 - nm);
    s = fmaf(s, fexp2(m - nm), e);
    m = nm;
}

// grouped-2 online LSE update
__device__ __forceinline__ void lse_upd2(float& m, float& s, float v0, float v1) {
    float m2 = fmaxf(v0, v1);
    float nm = fmaxf(m, m2);
    float e = fexp2(v0 - nm) + fexp2(v1 - nm);
    s = fmaf(s, fexp2(m - nm), e);
    m = nm;
}

// ---------------- init ----------------
__global__ void init_zero(float* __restrict__ g) {
    int t = blockIdx.x * 256 + threadIdx.x;
    if (t < NR) g[t] = 0.0f;
}

// ---------------- out[M,DIM] = A[M,DIM] @ W[DIM,DIM] + bias ----------------
__global__ __launch_bounds__(256) void gemm_qk(const float* __restrict__ A,
                                               const float* __restrict__ W,
                                               const float* __restrict__ bias,
                                               float* __restrict__ out) {
    __shared__ float As[16][68];
    __shared__ float Ws[16][68];
    const int t  = threadIdx.x;
    const int r0 = blockIdx.x * 64;
    const int c0 = blockIdx.y * 64;
    const int ty = t >> 4, tx = t & 15;
    const int arow = t >> 2;
    const int ak   = (t & 3) * 4;
    const int wrow = t >> 4;
    const int wcol = (t & 15) * 4;
    float acc[4][4] = {};
    for (int k0 = 0; k0 < DIM; k0 += 16) {
        float4 av = *(const float4*)(A + (size_t)(r0 + arow) * DIM + k0 + ak);
        float4 wv = *(const float4*)(W + (size_t)(k0 + wrow) * DIM + c0 + wcol);
        __syncthreads();
        As[ak + 0][arow] = av.x; As[ak + 1][arow] = av.y;
        As[ak + 2][arow] = av.z; As[ak + 3][arow] = av.w;
        *(float4*)&Ws[wrow][wcol] = wv;
        __syncthreads();
#pragma unroll
        for (int kk = 0; kk < 16; ++kk) {
            float4 a = *(const float4*)&As[kk][ty * 4];
            float4 b = *(const float4*)&Ws[kk][tx * 4];
            float aa[4] = {a.x, a.y, a.z, a.w};
            float bb[4] = {b.x, b.y, b.z, b.w};
#pragma unroll
            for (int i = 0; i < 4; ++i)
#pragma unroll
                for (int j = 0; j < 4; ++j)
                    acc[i][j] = fmaf(aa[i], bb[j], acc[i][j]);
        }
    }
#pragma unroll
    for (int i = 0; i < 4; ++i) {
        float4 o;
        o.x = acc[i][0] + bias[c0 + tx * 4 + 0];
        o.y = acc[i][1] + bias[c0 + tx * 4 + 1];
        o.z = acc[i][2] + bias[c0 + tx * 4 + 2];
        o.w = acc[i][3] + bias[c0 + tx * 4 + 3];
        *(float4*)(out + (size_t)(r0 + ty * 4 + i) * DIM + c0 + tx * 4) = o;
    }
}

// ---------------- row squared norms ----------------
__global__ __launch_bounds__(64) void row_norm(const float* __restrict__ x,
                                               float* __restrict__ out) {
    const int row = blockIdx.x, lane = threadIdx.x;
    float4 v = *(const float4*)(x + (size_t)row * DIM + lane * 4);
    float s = v.x * v.x + v.y * v.y + v.z * v.z + v.w * v.w;
#pragma unroll
    for (int off = 32; off > 0; off >>= 1) s += __shfl_xor(s, off);
    if (lane == 0) out[row] = s;
}

// ---------------- MLP logits: relu(A@W1+b1)@W2 + b2 ----------------
__global__ __launch_bounds__(128) void mlp_logits(const float* __restrict__ A,
                                                  const float* __restrict__ W1,
                                                  const float* __restrict__ b1,
                                                  const float* __restrict__ W2,
                                                  const float* __restrict__ b2,
                                                  float* __restrict__ logits) {
    __shared__ float ar[DIM];
    __shared__ float red[2];
    const int t = threadIdx.x;
    const int row = blockIdx.x;
    *(float2*)&ar[t * 2] = *(const float2*)(A + (size_t)row * DIM + t * 2);
    __syncthreads();
    float h = b1[t];
#pragma unroll 8
    for (int kk = 0; kk < DIM; ++kk) h = fmaf(ar[kk], W1[kk * 128 + t], h);
    float val = fmaxf(h, 0.0f) * W2[t];
#pragma unroll
    for (int off = 32; off > 0; off >>= 1) val += __shfl_xor(val, off);
    if ((t & 63) == 0) red[t >> 6] = val;
    __syncthreads();
    if (t == 0) logits[row] = red[0] + red[1] + b2[0];
}

// ---------------- softmax over 8192 logits -> log2(b + 1e-20) ----------------
__global__ __launch_bounds__(1024) void softmax_logb(const float* __restrict__ logits,
                                                     float* __restrict__ logb2) {
    __shared__ float redm[16], reds[16];
    const int t = threadIdx.x;
    float l[8];
    float m = -INFINITY;
#pragma unroll
    for (int i = 0; i < 8; ++i) { l[i] = logits[i * 1024 + t]; m = fmaxf(m, l[i]); }
#pragma unroll
    for (int off = 32; off > 0; off >>= 1) m = fmaxf(m, __shfl_xor(m, off));
    if ((t & 63) == 0) redm[t >> 6] = m;
    __syncthreads();
    if (t < 64) {
        float v = (t < 16) ? redm[t] : -INFINITY;
#pragma unroll
        for (int off = 8; off > 0; off >>= 1) v = fmaxf(v, __shfl_xor(v, off));
        if (t == 0) redm[0] = v;
    }
    __syncthreads();
    m = redm[0];
    float s = 0.0f;
#pragma unroll
    for (int i = 0; i < 8; ++i) s += __expf(l[i] - m);
#pragma unroll
    for (int off = 32; off > 0; off >>= 1) s += __shfl_xor(s, off);
    if ((t & 63) == 0) reds[t >> 6] = s;
    __syncthreads();
    if (t < 64) {
        float v = (t < 16) ? reds[t] : 0.0f;
#pragma unroll
        for (int off = 8; off > 0; off >>= 1) v += __shfl_xor(v, off);
        if (t == 0) reds[0] = v;
    }
    __syncthreads();
    s = reds[0];
    float invs = 1.0f / s;
#pragma unroll
    for (int i = 0; i < 8; ++i)
        logb2[i * 1024 + t] = log2f(__expf(l[i] - m) * invs + 1e-20f);
}

// ---------------- S[i][j] = log2e*10*(qn_i + kn_j - 2*q_i.k_j) ----------------
__global__ __launch_bounds__(256) void dist_kernel(const float* __restrict__ q,
                                                   const float* __restrict__ k,
                                                   const float* __restrict__ qn,
                                                   const float* __restrict__ kn,
                                                   float* __restrict__ S) {
    __shared__ float Qs[16][132];
    __shared__ float Ks[16][132];
    const int t  = threadIdx.x;
    const int r0 = blockIdx.y * 128;
    const int c0 = blockIdx.x * 128;
    const int lrow = t >> 1;
    const int lk   = (t & 1) * 8;
    const int wv   = t >> 6;
    const int lane = t & 63;
    const int ty8 = (wv >> 1) * 8 + (lane >> 3);
    const int tx8 = (wv & 1) * 8 + (lane & 7);
    float acc[8][8] = {};
    for (int k0 = 0; k0 < DIM; k0 += 16) {
        float4 qa = *(const float4*)(q + (size_t)(r0 + lrow) * DIM + k0 + lk);
        float4 qb = *(const float4*)(q + (size_t)(r0 + lrow) * DIM + k0 + lk + 4);
        float4 ka = *(const float4*)(k + (size_t)(c0 + lrow) * DIM + k0 + lk);
        float4 kb = *(const float4*)(k + (size_t)(c0 + lrow) * DIM + k0 + lk + 4);
        __syncthreads();
        Qs[lk + 0][lrow] = qa.x; Qs[lk + 1][lrow] = qa.y;
        Qs[lk + 2][lrow] = qa.z; Qs[lk + 3][lrow] = qa.w;
        Qs[lk + 4][lrow] = qb.x; Qs[lk + 5][lrow] = qb.y;
        Qs[lk + 6][lrow] = qb.z; Qs[lk + 7][lrow] = qb.w;
        Ks[lk + 0][lrow] = ka.x; Ks[lk + 1][lrow] = ka.y;
        Ks[lk + 2][lrow] = ka.z; Ks[lk + 3][lrow] = ka.w;
        Ks[lk + 4][lrow] = kb.x; Ks[lk + 5][lrow] = kb.y;
        Ks[lk + 6][lrow] = kb.z; Ks[lk + 7][lrow] = kb.w;
        __syncthreads();
#pragma unroll
        for (int kk = 0; kk < 16; ++kk) {
            float4 a0 = *(const float4*)&Qs[kk][ty8 * 8];
            float4 a1 = *(const float4*)&Qs[kk][ty8 * 8 + 4];
            float4 b0 = *(const float4*)&Ks[kk][tx8 * 8];
            float4 b1 = *(const float4*)&Ks[kk][tx8 * 8 + 4];
            float aa[8] = {a0.x, a0.y, a0.z, a0.w, a1.x, a1.y, a1.z, a1.w};
            float bb[8] = {b0.x, b0.y, b0.z, b0.w, b1.x, b1.y, b1.z, b1.w};
#pragma unroll
            for (int i = 0; i < 8; ++i)
#pragma unroll
                for (int j = 0; j < 8; ++j)
                    acc[i][j] = fmaf(aa[i], bb[j], acc[i][j]);
        }
    }
    float knv[8];
#pragma unroll
    for (int j = 0; j < 8; ++j) knv[j] = kn[c0 + tx8 * 8 + j];
#pragma unroll
    for (int i = 0; i < 8; ++i) {
        const int row = r0 + ty8 * 8 + i;
        const float qni = qn[row];
        float* outp = S + (size_t)row * NR + c0 + tx8 * 8;
        float4 o0, o1;
        o0.x = (qni + knv[0] - 2.0f * acc[i][0]) * SCALE2;
        o0.y = (qni + knv[1] - 2.0f * acc[i][1]) * SCALE2;
        o0.z = (qni + knv[2] - 2.0f * acc[i][2]) * SCALE2;
        o0.w = (qni + knv[3] - 2.0f * acc[i][3]) * SCALE2;
        o1.x = (qni + knv[4] - 2.0f * acc[i][4]) * SCALE2;
        o1.y = (qni + knv[5] - 2.0f * acc[i][5]) * SCALE2;
        o1.z = (qni + knv[6] - 2.0f * acc[i][6]) * SCALE2;
        o1.w = (qni + knv[7] - 2.0f * acc[i][7]) * SCALE2;
        *(float4*)outp = o0;
        *(float4*)(outp + 4) = o1;
    }
}

// ---------------- fused iteration: pipelined row LSE + column partials ----------------
// 256 blocks (1/CU) x 512 threads (8 waves), 32 rows per block, 2-row sub-chunks.
// Double-buffered LDS staging (2 x 64 KB) + double-buffered reduction scratch give
// ONE barrier per sub-chunk. The next sub-chunk's global loads are issued right
// after the barrier, so they stream (HBM) while f-compute + column-accumulate
// (VALU+LDS) run — first use of rbuf is next iteration's row-LSE, so the
// compiler's vmcnt wait lands after phase 2. g is preloaded to registers once.
__global__ __launch_bounds__(512, 2) void iter_fused(const float* __restrict__ S,
                                                     const float* __restrict__ g,
                                                     const float* __restrict__ logb2,
                                                     float* __restrict__ f,
                                                     float2* __restrict__ pms) {
    __shared__ float Sbuf[2][RSC][NR];   // 128 KB staging (double-buffered)
    __shared__ float redm[2][8], reds[2][8];
    const int t = threadIdx.x;
    const int wv = t >> 6, lane = t & 63;
    const int chunk = blockIdx.x;
    const int r0 = chunk * CROWS;
    const int rw = wv >> 2;              // row (0..1) within sub-chunk
    const int qt = wv & 3;               // quarter of the row this wave scans
    const int qbase = qt * 2048;
    const int loff = lane * 4;

    // preload this wave's g quarter (g is constant within one launch)
    float4 greg[8];
#pragma unroll
    for (int it = 0; it < 8; ++it)
        greg[it] = *(const float4*)(g + qbase + it * 256 + loff);

    // column accumulators: thread t owns cols {j*2048 + t*4 + c}
    float cm[4][4], cs[4][4];
#pragma unroll
    for (int j = 0; j < 4; ++j)
#pragma unroll
        for (int c = 0; c < 4; ++c) { cm[j][c] = -INFINITY; cs[j][c] = 0.0f; }

    // prime: load sub-chunk 0 into registers
    float4 rbuf[8];
    {
        const float* Sr = S + (size_t)(r0 + rw) * NR + qbase;
#pragma unroll
        for (int it = 0; it < 8; ++it)
            rbuf[it] = *(const float4*)(Sr + it * 256 + loff);
    }

#pragma unroll
    for (int sc = 0; sc < NSUB; ++sc) {
        const int buf = sc & 1;
        // ---- row-LSE over this wave's 32 values (rbuf + g) ----
        float m = -INFINITY, s = 0.0f;
#pragma unroll
        for (int it = 0; it < 8; ++it) {
            float4 v = rbuf[it];
            float4 gv = greg[it];
            lse_upd4(m, s, v.x + gv.x, v.y + gv.y, v.z + gv.z, v.w + gv.w);
        }
        // ---- stage rbuf to LDS ----
#pragma unroll
        for (int it = 0; it < 8; ++it)
            *(float4*)&Sbuf[buf][rw][qbase + it * 256 + loff] = rbuf[it];
        // ---- wave reduce ----
#pragma unroll
        for (int off = 32; off > 0; off >>= 1) {
            float mo = __shfl_xor(m, off);
            float so = __shfl_xor(s, off);
            lse_comb2(m, s, mo, so);
        }
        if (lane == 0) { redm[buf][wv] = m; reds[buf][wv] = s; }
        __syncthreads();   // Sbuf[buf] + red[buf] visible

        // ---- prefetch next sub-chunk (streams during f-compute + phase 2) ----
        if (sc + 1 < NSUB) {
            const float* Sn = S + (size_t)(r0 + (sc + 1) * RSC + rw) * NR + qbase;
#pragma unroll
            for (int it = 0; it < 8; ++it)
                rbuf[it] = *(const float4*)(Sn + it * 256 + loff);
        }

        // ---- all threads: combine 4 quarter-row partials -> f0, f1 ----
        float fr[RSC];
#pragma unroll
        for (int r = 0; r < RSC; ++r) {
            float mm = redm[buf][r * 4 + 0], ss = reds[buf][r * 4 + 0];
            lse_comb2(mm, ss, redm[buf][r * 4 + 1], reds[buf][r * 4 + 1]);
            lse_comb2(mm, ss, redm[buf][r * 4 + 2], reds[buf][r * 4 + 2]);
            lse_comb2(mm, ss, redm[buf][r * 4 + 3], reds[buf][r * 4 + 3]);
            fr[r] = logb2[r0 + sc * RSC + r] - (mm + flog2(ss));
        }
        if (t < RSC) f[r0 + sc * RSC + t] = fr[t];

        // ---- phase 2: column partial-LSE over the 2 staged rows (LDS reads) ----
#pragma unroll
        for (int j = 0; j < 4; ++j) {
            const int c = j * 2048 + t * 4;
            float4 a = *(const float4*)&Sbuf[buf][0][c];
            float4 b = *(const float4*)&Sbuf[buf][1][c];
            lse_upd2(cm[j][0], cs[j][0], a.x + fr[0], b.x + fr[1]);
            lse_upd2(cm[j][1], cs[j][1], a.y + fr[0], b.y + fr[1]);
            lse_upd2(cm[j][2], cs[j][2], a.z + fr[0], b.z + fr[1]);
            lse_upd2(cm[j][3], cs[j][3], a.w + fr[0], b.w + fr[1]);
        }
        // no second barrier: next sub-chunk writes the OTHER Sbuf/red buffer
    }
    // write column partials for this chunk
#pragma unroll
    for (int j = 0; j < 4; ++j) {
        float2* o = pms + (size_t)chunk * NR + j * 2048 + t * 4;
        o[0] = make_float2(cm[j][0], cs[j][0]);
        o[1] = make_float2(cm[j][1], cs[j][1]);
        o[2] = make_float2(cm[j][2], cs[j][2]);
        o[3] = make_float2(cm[j][3], cs[j][3]);
    }
}

// ---------------- combine partials -> g ----------------
__global__ __launch_bounds__(256) void col_combine(const float2* __restrict__ pms,
                                                   float* __restrict__ g,
                                                   float log_a2) {
    const int col = blockIdx.x * 256 + threadIdx.x;
    float m = -INFINITY, s = 0.0f;
#pragma unroll 8
    for (int ch = 0; ch < NBLK; ++ch) {
        float2 p = pms[(size_t)ch * NR + col];
        lse_comb2(m, s, p.x, p.y);
    }
    g[col] = log_a2 - (m + flog2(s));
}

// ---------------- T = exp2(f + S + g), in place; global sum == 1 analytically ----------------
// note: no __restrict__ on S/out — they alias (in-place)
__global__ __launch_bounds__(256) void write_pass(const float* S,
                                                  const float* __restrict__ f,
                                                  const float* __restrict__ g,
                                                  float* out) {
    const int wv = threadIdx.x >> 6, lane = threadIdx.x & 63;
    const int row = blockIdx.x * 4 + wv;
    const float fi = f[row];
    const float4* Sr = (const float4*)(S + (size_t)row * NR);
    const float4* gr = (const float4*)g;
    float4* Or = (float4*)(out + (size_t)row * NR);
#pragma unroll 4
    for (int it = 0; it < NR / 256; ++it) {
        const int idx = it * 64 + lane;
        float4 sv = Sr[idx];
        float4 gv = gr[idx];
        float4 o;
        o.x = fexp2(fi + sv.x + gv.x);
        o.y = fexp2(fi + sv.y + gv.y);
        o.z = fexp2(fi + sv.z + gv.z);
        o.w = fexp2(fi + sv.w + gv.w);
        Or[idx] = o;
    }
}

extern "C" void kernel_launch(void* const* d_in, const int* in_sizes, int n_in,
                              void* d_out, int out_size, void* d_ws, size_t ws_size,
                              hipStream_t stream) {
    (void)in_sizes; (void)n_in; (void)out_size; (void)ws_size;
    const float* A  = (const float*)d_in[0];
    const float* Tk = (const float*)d_in[1];
    const float* Wq = (const float*)d_in[2];
    const float* bq = (const float*)d_in[3];
    const float* Wk = (const float*)d_in[4];
    const float* bk = (const float*)d_in[5];
    const float* W1 = (const float*)d_in[6];
    const float* b1 = (const float*)d_in[7];
    const float* W2 = (const float*)d_in[8];
    const float* b2 = (const float*)d_in[9];
    float* S  = (float*)d_out;           // 8192x8192 base-2 log_K lives in d_out
    float* ws = (float*)d_ws;
    float* qn     = ws; ws += NR;
    float* kn     = ws; ws += NR;
    float* logb2  = ws; ws += NR;
    float* logits = ws; ws += NR;
    float* f      = ws; ws += NR;
    float* g      = ws; ws += NR;
    float2* pms   = (float2*)ws;         // NBLK * NR float2 = 16 MB
    // q,k (8 MB each) overlay the pms region: dist phase completes before any
    // partial is written, and q/k are dead once dist_kernel finishes.
    float* q = (float*)pms;
    float* k = q + (size_t)NR * DIM;

    const float log_a2 = -13.0f; // log2(1/8192 + 1e-20)

    init_zero<<<32, 256, 0, stream>>>(g);
    gemm_qk<<<dim3(128, 4), 256, 0, stream>>>(A, Wq, bq, q);
    gemm_qk<<<dim3(128, 4), 256, 0, stream>>>(Tk, Wk, bk, k);
    row_norm<<<NR, 64, 0, stream>>>(q, qn);
    row_norm<<<NR, 64, 0, stream>>>(k, kn);
    mlp_logits<<<NR, 128, 0, stream>>>(A, W1, b1, W2, b2, logits);
    softmax_logb<<<1, 1024, 0, stream>>>(logits, logb2);
    dist_kernel<<<dim3(64, 64), 256, 0, stream>>>(q, k, qn, kn, S);
    for (int it = 0; it < 50; ++it) {
        iter_fused<<<NBLK, 512, 0, stream>>>(S, g, logb2, f, pms);
        col_combine<<<32, 256, 0, stream>>>(pms, g, log_a2);
    }
    write_pass<<<NR / 4, 256, 0, stream>>>(S, f, g, S);
}

// Round 9
// 5045.055 us; speedup vs baseline: 1.7850x; 1.7850x over previous
//
#include <hip/hip_runtime.h>
#include <math.h>

#define NR 8192      // NA == NT
#define DIM 256
#define NBLK 512     // fused-kernel blocks == column-partial chunks (2 per CU)
#define CROWS 16     // rows per chunk
#define RSC 2        // rows per sub-chunk
#define NSUB 8       // sub-chunks per chunk
// 10 * log2(e): converts distances directly into base-2 log domain
#define SCALE2 14.426950408889634f

// v_exp_f32 / v_log_f32 are base-2 natively — use them raw
__device__ __forceinline__ float fexp2(float x) {
#if __has_builtin(__builtin_amdgcn_exp2f)
    return __builtin_amdgcn_exp2f(x);
#else
    return exp2f(x);
#endif
}
__device__ __forceinline__ float flog2(float x) {
#if __has_builtin(__builtin_amdgcn_logf)
    return __builtin_amdgcn_logf(x);
#else
    return log2f(x);
#endif
}

// base-2 online LSE combine
__device__ __forceinline__ void lse_comb2(float& m, float& s, float mo, float so) {
    float nm = fmaxf(m, mo);
    s = s * fexp2(m - nm) + so * fexp2(mo - nm);
    m = nm;
}

// grouped-4 online LSE update (1 tree-max + 1 correction exp per 4 values)
__device__ __forceinline__ void lse_upd4(float& m, float& s,
                                         float v0, float v1, float v2, float v3) {
    float m4 = fmaxf(fmaxf(v0, v1), fmaxf(v2, v3));
    float nm = fmaxf(m, m4);
    float e = fexp2(v0 - nm) + fexp2(v1 - nm) + fexp2(v2 - nm) + fexp2(v3 - nm);
    s = fmaf(s, fexp2(m - nm), e);
    m = nm;
}

// grouped-2 online LSE update
__device__ __forceinline__ void lse_upd2(float& m, float& s, float v0, float v1) {
    float m2 = fmaxf(v0, v1);
    float nm = fmaxf(m, m2);
    float e = fexp2(v0 - nm) + fexp2(v1 - nm);
    s = fmaf(s, fexp2(m - nm), e);
    m = nm;
}

// ---------------- init ----------------
__global__ void init_zero(float* __restrict__ g) {
    int t = blockIdx.x * 256 + threadIdx.x;
    if (t < NR) g[t] = 0.0f;
}

// ---------------- out[M,DIM] = A[M,DIM] @ W[DIM,DIM] + bias ----------------
__global__ __launch_bounds__(256) void gemm_qk(const float* __restrict__ A,
                                               const float* __restrict__ W,
                                               const float* __restrict__ bias,
                                               float* __restrict__ out) {
    __shared__ float As[16][68];
    __shared__ float Ws[16][68];
    const int t  = threadIdx.x;
    const int r0 = blockIdx.x * 64;
    const int c0 = blockIdx.y * 64;
    const int ty = t >> 4, tx = t & 15;
    const int arow = t >> 2;
    const int ak   = (t & 3) * 4;
    const int wrow = t >> 4;
    const int wcol = (t & 15) * 4;
    float acc[4][4] = {};
    for (int k0 = 0; k0 < DIM; k0 += 16) {
        float4 av = *(const float4*)(A + (size_t)(r0 + arow) * DIM + k0 + ak);
        float4 wv = *(const float4*)(W + (size_t)(k0 + wrow) * DIM + c0 + wcol);
        __syncthreads();
        As[ak + 0][arow] = av.x; As[ak + 1][arow] = av.y;
        As[ak + 2][arow] = av.z; As[ak + 3][arow] = av.w;
        *(float4*)&Ws[wrow][wcol] = wv;
        __syncthreads();
#pragma unroll
        for (int kk = 0; kk < 16; ++kk) {
            float4 a = *(const float4*)&As[kk][ty * 4];
            float4 b = *(const float4*)&Ws[kk][tx * 4];
            float aa[4] = {a.x, a.y, a.z, a.w};
            float bb[4] = {b.x, b.y, b.z, b.w};
#pragma unroll
            for (int i = 0; i < 4; ++i)
#pragma unroll
                for (int j = 0; j < 4; ++j)
                    acc[i][j] = fmaf(aa[i], bb[j], acc[i][j]);
        }
    }
#pragma unroll
    for (int i = 0; i < 4; ++i) {
        float4 o;
        o.x = acc[i][0] + bias[c0 + tx * 4 + 0];
        o.y = acc[i][1] + bias[c0 + tx * 4 + 1];
        o.z = acc[i][2] + bias[c0 + tx * 4 + 2];
        o.w = acc[i][3] + bias[c0 + tx * 4 + 3];
        *(float4*)(out + (size_t)(r0 + ty * 4 + i) * DIM + c0 + tx * 4) = o;
    }
}

// ---------------- row squared norms ----------------
__global__ __launch_bounds__(64) void row_norm(const float* __restrict__ x,
                                               float* __restrict__ out) {
    const int row = blockIdx.x, lane = threadIdx.x;
    float4 v = *(const float4*)(x + (size_t)row * DIM + lane * 4);
    float s = v.x * v.x + v.y * v.y + v.z * v.z + v.w * v.w;
#pragma unroll
    for (int off = 32; off > 0; off >>= 1) s += __shfl_xor(s, off);
    if (lane == 0) out[row] = s;
}

// ---------------- MLP logits: relu(A@W1+b1)@W2 + b2 ----------------
__global__ __launch_bounds__(128) void mlp_logits(const float* __restrict__ A,
                                                  const float* __restrict__ W1,
                                                  const float* __restrict__ b1,
                                                  const float* __restrict__ W2,
                                                  const float* __restrict__ b2,
                                                  float* __restrict__ logits) {
    __shared__ float ar[DIM];
    __shared__ float red[2];
    const int t = threadIdx.x;
    const int row = blockIdx.x;
    *(float2*)&ar[t * 2] = *(const float2*)(A + (size_t)row * DIM + t * 2);
    __syncthreads();
    float h = b1[t];
#pragma unroll 8
    for (int kk = 0; kk < DIM; ++kk) h = fmaf(ar[kk], W1[kk * 128 + t], h);
    float val = fmaxf(h, 0.0f) * W2[t];
#pragma unroll
    for (int off = 32; off > 0; off >>= 1) val += __shfl_xor(val, off);
    if ((t & 63) == 0) red[t >> 6] = val;
    __syncthreads();
    if (t == 0) logits[row] = red[0] + red[1] + b2[0];
}

// ---------------- softmax over 8192 logits -> log2(b + 1e-20) ----------------
__global__ __launch_bounds__(1024) void softmax_logb(const float* __restrict__ logits,
                                                     float* __restrict__ logb2) {
    __shared__ float redm[16], reds[16];
    const int t = threadIdx.x;
    float l[8];
    float m = -INFINITY;
#pragma unroll
    for (int i = 0; i < 8; ++i) { l[i] = logits[i * 1024 + t]; m = fmaxf(m, l[i]); }
#pragma unroll
    for (int off = 32; off > 0; off >>= 1) m = fmaxf(m, __shfl_xor(m, off));
    if ((t & 63) == 0) redm[t >> 6] = m;
    __syncthreads();
    if (t < 64) {
        float v = (t < 16) ? redm[t] : -INFINITY;
#pragma unroll
        for (int off = 8; off > 0; off >>= 1) v = fmaxf(v, __shfl_xor(v, off));
        if (t == 0) redm[0] = v;
    }
    __syncthreads();
    m = redm[0];
    float s = 0.0f;
#pragma unroll
    for (int i = 0; i < 8; ++i) s += __expf(l[i] - m);
#pragma unroll
    for (int off = 32; off > 0; off >>= 1) s += __shfl_xor(s, off);
    if ((t & 63) == 0) reds[t >> 6] = s;
    __syncthreads();
    if (t < 64) {
        float v = (t < 16) ? reds[t] : 0.0f;
#pragma unroll
        for (int off = 8; off > 0; off >>= 1) v += __shfl_xor(v, off);
        if (t == 0) reds[0] = v;
    }
    __syncthreads();
    s = reds[0];
    float invs = 1.0f / s;
#pragma unroll
    for (int i = 0; i < 8; ++i)
        logb2[i * 1024 + t] = log2f(__expf(l[i] - m) * invs + 1e-20f);
}

// ---------------- S[i][j] = log2e*10*(qn_i + kn_j - 2*q_i.k_j) ----------------
__global__ __launch_bounds__(256) void dist_kernel(const float* __restrict__ q,
                                                   const float* __restrict__ k,
                                                   const float* __restrict__ qn,
                                                   const float* __restrict__ kn,
                                                   float* __restrict__ S) {
    __shared__ float Qs[16][132];
    __shared__ float Ks[16][132];
    const int t  = threadIdx.x;
    const int r0 = blockIdx.y * 128;
    const int c0 = blockIdx.x * 128;
    const int lrow = t >> 1;
    const int lk   = (t & 1) * 8;
    const int wv   = t >> 6;
    const int lane = t & 63;
    const int ty8 = (wv >> 1) * 8 + (lane >> 3);
    const int tx8 = (wv & 1) * 8 + (lane & 7);
    float acc[8][8] = {};
    for (int k0 = 0; k0 < DIM; k0 += 16) {
        float4 qa = *(const float4*)(q + (size_t)(r0 + lrow) * DIM + k0 + lk);
        float4 qb = *(const float4*)(q + (size_t)(r0 + lrow) * DIM + k0 + lk + 4);
        float4 ka = *(const float4*)(k + (size_t)(c0 + lrow) * DIM + k0 + lk);
        float4 kb = *(const float4*)(k + (size_t)(c0 + lrow) * DIM + k0 + lk + 4);
        __syncthreads();
        Qs[lk + 0][lrow] = qa.x; Qs[lk + 1][lrow] = qa.y;
        Qs[lk + 2][lrow] = qa.z; Qs[lk + 3][lrow] = qa.w;
        Qs[lk + 4][lrow] = qb.x; Qs[lk + 5][lrow] = qb.y;
        Qs[lk + 6][lrow] = qb.z; Qs[lk + 7][lrow] = qb.w;
        Ks[lk + 0][lrow] = ka.x; Ks[lk + 1][lrow] = ka.y;
        Ks[lk + 2][lrow] = ka.z; Ks[lk + 3][lrow] = ka.w;
        Ks[lk + 4][lrow] = kb.x; Ks[lk + 5][lrow] = kb.y;
        Ks[lk + 6][lrow] = kb.z; Ks[lk + 7][lrow] = kb.w;
        __syncthreads();
#pragma unroll
        for (int kk = 0; kk < 16; ++kk) {
            float4 a0 = *(const float4*)&Qs[kk][ty8 * 8];
            float4 a1 = *(const float4*)&Qs[kk][ty8 * 8 + 4];
            float4 b0 = *(const float4*)&Ks[kk][tx8 * 8];
            float4 b1 = *(const float4*)&Ks[kk][tx8 * 8 + 4];
            float aa[8] = {a0.x, a0.y, a0.z, a0.w, a1.x, a1.y, a1.z, a1.w};
            float bb[8] = {b0.x, b0.y, b0.z, b0.w, b1.x, b1.y, b1.z, b1.w};
#pragma unroll
            for (int i = 0; i < 8; ++i)
#pragma unroll
                for (int j = 0; j < 8; ++j)
                    acc[i][j] = fmaf(aa[i], bb[j], acc[i][j]);
        }
    }
    float knv[8];
#pragma unroll
    for (int j = 0; j < 8; ++j) knv[j] = kn[c0 + tx8 * 8 + j];
#pragma unroll
    for (int i = 0; i < 8; ++i) {
        const int row = r0 + ty8 * 8 + i;
        const float qni = qn[row];
        float* outp = S + (size_t)row * NR + c0 + tx8 * 8;
        float4 o0, o1;
        o0.x = (qni + knv[0] - 2.0f * acc[i][0]) * SCALE2;
        o0.y = (qni + knv[1] - 2.0f * acc[i][1]) * SCALE2;
        o0.z = (qni + knv[2] - 2.0f * acc[i][2]) * SCALE2;
        o0.w = (qni + knv[3] - 2.0f * acc[i][3]) * SCALE2;
        o1.x = (qni + knv[4] - 2.0f * acc[i][4]) * SCALE2;
        o1.y = (qni + knv[5] - 2.0f * acc[i][5]) * SCALE2;
        o1.z = (qni + knv[6] - 2.0f * acc[i][6]) * SCALE2;
        o1.w = (qni + knv[7] - 2.0f * acc[i][7]) * SCALE2;
        *(float4*)outp = o0;
        *(float4*)(outp + 4) = o1;
    }
}

// ---------------- fused iteration: row LSE + column partials, LDS-staged ----------------
// Round-7 structure (proven) at 2-blocks/CU topology: 512 blocks x 512 threads,
// 16 rows per block, 2-row sub-chunks, 64 KB LDS staging -> two blocks co-resident
// per CU. While one block is in its barrier/phase-2 (VALU+LDS), the sibling block
// streams phase-1 HBM — overlap via occupancy, not intra-block pipelining (which
// regressed in rounds 6 and 8). Partials are stored as a single float
// L = m + log2(s) (exact LSE identity), halving partial traffic.
__global__ __launch_bounds__(512, 4) void iter_fused(const float* __restrict__ S,
                                                     const float* __restrict__ g,
                                                     const float* __restrict__ logb2,
                                                     float* __restrict__ f,
                                                     float* __restrict__ pm) {
    __shared__ float Srow[RSC][NR];   // 64 KB staging
    __shared__ float redm[8], reds[8];
    const int t = threadIdx.x;
    const int wv = t >> 6, lane = t & 63;
    const int chunk = blockIdx.x;
    const int r0 = chunk * CROWS;
    const int rw = wv >> 2;           // row (0..1) within sub-chunk
    const int qt = wv & 3;            // quarter of the row this wave scans
    const int qbase = qt * 2048;
    const int loff = lane * 4;

    // preload this wave's g quarter (constant within one launch): 8 float4
    float4 greg[8];
#pragma unroll
    for (int it = 0; it < 8; ++it)
        greg[it] = *(const float4*)(g + qbase + it * 256 + loff);

    // column accumulators: thread t owns cols {j*2048 + t*4 + c}
    float cm[4][4], cs[4][4];
#pragma unroll
    for (int j = 0; j < 4; ++j)
#pragma unroll
        for (int c = 0; c < 4; ++c) { cm[j][c] = -INFINITY; cs[j][c] = 0.0f; }

    for (int sc = 0; sc < NSUB; ++sc) {
        // ---- phase 1: scan row (r0 + sc*2 + rw), quarter qt, stage to LDS ----
        const int row = r0 + sc * RSC + rw;
        const float* Sr = S + (size_t)row * NR + qbase;
        float m = -INFINITY, s = 0.0f;
#pragma unroll
        for (int it = 0; it < 8; ++it) {
            float4 sv = *(const float4*)(Sr + it * 256 + loff);
            *(float4*)&Srow[rw][qbase + it * 256 + loff] = sv;
            float4 gv = greg[it];
            lse_upd4(m, s, sv.x + gv.x, sv.y + gv.y, sv.z + gv.z, sv.w + gv.w);
        }
#pragma unroll
        for (int off = 32; off > 0; off >>= 1) {
            float mo = __shfl_xor(m, off);
            float so = __shfl_xor(s, off);
            lse_comb2(m, s, mo, so);
        }
        if (lane == 0) { redm[wv] = m; reds[wv] = s; }
        __syncthreads();   // LDS staging + red arrays visible

        // ---- all threads: combine 4 quarter-row partials -> f0, f1 ----
        float fr[RSC];
#pragma unroll
        for (int r = 0; r < RSC; ++r) {
            float mm = redm[r * 4 + 0], ss = reds[r * 4 + 0];
            lse_comb2(mm, ss, redm[r * 4 + 1], reds[r * 4 + 1]);
            lse_comb2(mm, ss, redm[r * 4 + 2], reds[r * 4 + 2]);
            lse_comb2(mm, ss, redm[r * 4 + 3], reds[r * 4 + 3]);
            fr[r] = logb2[r0 + sc * RSC + r] - (mm + flog2(ss));
        }
        if (t < RSC) f[r0 + sc * RSC + t] = fr[t];

        // ---- phase 2: column partial-LSE over the 2 staged rows (LDS reads) ----
#pragma unroll
        for (int j = 0; j < 4; ++j) {
            const int c = j * 2048 + t * 4;
            float4 a = *(const float4*)&Srow[0][c];
            float4 b = *(const float4*)&Srow[1][c];
            lse_upd2(cm[j][0], cs[j][0], a.x + fr[0], b.x + fr[1]);
            lse_upd2(cm[j][1], cs[j][1], a.y + fr[0], b.y + fr[1]);
            lse_upd2(cm[j][2], cs[j][2], a.z + fr[0], b.z + fr[1]);
            lse_upd2(cm[j][3], cs[j][3], a.w + fr[0], b.w + fr[1]);
        }
        __syncthreads();   // protect Srow before next sub-chunk overwrites it
    }
    // write column partials for this chunk as L = m + log2(s)
#pragma unroll
    for (int j = 0; j < 4; ++j) {
        float4 L;
        L.x = cm[j][0] + flog2(cs[j][0]);
        L.y = cm[j][1] + flog2(cs[j][1]);
        L.z = cm[j][2] + flog2(cs[j][2]);
        L.w = cm[j][3] + flog2(cs[j][3]);
        *(float4*)&pm[(size_t)chunk * NR + j * 2048 + t * 4] = L;
    }
}

// ---------------- combine partials -> g ----------------
__global__ __launch_bounds__(256) void col_combine(const float* __restrict__ pm,
                                                   float* __restrict__ g,
                                                   float log_a2) {
    const int col = blockIdx.x * 256 + threadIdx.x;
    float m = -INFINITY, s = 0.0f;
#pragma unroll 4
    for (int ch = 0; ch < NBLK; ch += 4) {
        float l0 = pm[(size_t)(ch + 0) * NR + col];
        float l1 = pm[(size_t)(ch + 1) * NR + col];
        float l2 = pm[(size_t)(ch + 2) * NR + col];
        float l3 = pm[(size_t)(ch + 3) * NR + col];
        lse_upd4(m, s, l0, l1, l2, l3);
    }
    g[col] = log_a2 - (m + flog2(s));
}

// ---------------- T = exp2(f + S + g), in place; global sum == 1 analytically ----------------
// note: no __restrict__ on S/out — they alias (in-place)
__global__ __launch_bounds__(256) void write_pass(const float* S,
                                                  const float* __restrict__ f,
                                                  const float* __restrict__ g,
                                                  float* out) {
    const int wv = threadIdx.x >> 6, lane = threadIdx.x & 63;
    const int row = blockIdx.x * 4 + wv;
    const float fi = f[row];
    const float4* Sr = (const float4*)(S + (size_t)row * NR);
    const float4* gr = (const float4*)g;
    float4* Or = (float4*)(out + (size_t)row * NR);
#pragma unroll 4
    for (int it = 0; it < NR / 256; ++it) {
        const int idx = it * 64 + lane;
        float4 sv = Sr[idx];
        float4 gv = gr[idx];
        float4 o;
        o.x = fexp2(fi + sv.x + gv.x);
        o.y = fexp2(fi + sv.y + gv.y);
        o.z = fexp2(fi + sv.z + gv.z);
        o.w = fexp2(fi + sv.w + gv.w);
        Or[idx] = o;
    }
}

extern "C" void kernel_launch(void* const* d_in, const int* in_sizes, int n_in,
                              void* d_out, int out_size, void* d_ws, size_t ws_size,
                              hipStream_t stream) {
    (void)in_sizes; (void)n_in; (void)out_size; (void)ws_size;
    const float* A  = (const float*)d_in[0];
    const float* Tk = (const float*)d_in[1];
    const float* Wq = (const float*)d_in[2];
    const float* bq = (const float*)d_in[3];
    const float* Wk = (const float*)d_in[4];
    const float* bk = (const float*)d_in[5];
    const float* W1 = (const float*)d_in[6];
    const float* b1 = (const float*)d_in[7];
    const float* W2 = (const float*)d_in[8];
    const float* b2 = (const float*)d_in[9];
    float* S  = (float*)d_out;           // 8192x8192 base-2 log_K lives in d_out
    float* ws = (float*)d_ws;
    float* qn     = ws; ws += NR;
    float* kn     = ws; ws += NR;
    float* logb2  = ws; ws += NR;
    float* logits = ws; ws += NR;
    float* f      = ws; ws += NR;
    float* g      = ws; ws += NR;
    float* pm     = ws;                  // NBLK * NR floats = 16 MB
    // q,k (8 MB each) overlay the pm region: dist phase completes before any
    // partial is written, and q/k are dead once dist_kernel finishes.
    float* q = pm;
    float* k = q + (size_t)NR * DIM;

    const float log_a2 = -13.0f; // log2(1/8192 + 1e-20)

    init_zero<<<32, 256, 0, stream>>>(g);
    gemm_qk<<<dim3(128, 4), 256, 0, stream>>>(A, Wq, bq, q);
    gemm_qk<<<dim3(128, 4), 256, 0, stream>>>(Tk, Wk, bk, k);
    row_norm<<<NR, 64, 0, stream>>>(q, qn);
    row_norm<<<NR, 64, 0, stream>>>(k, kn);
    mlp_logits<<<NR, 128, 0, stream>>>(A, W1, b1, W2, b2, logits);
    softmax_logb<<<1, 1024, 0, stream>>>(logits, logb2);
    dist_kernel<<<dim3(64, 64), 256, 0, stream>>>(q, k, qn, kn, S);
    for (int it = 0; it < 50; ++it) {
        iter_fused<<<NBLK, 512, 0, stream>>>(S, g, logb2, f, pm);
        col_combine<<<32, 256, 0, stream>>>(pm, g, log_a2);
    }
    write_pass<<<NR / 4, 256, 0, stream>>>(S, f, g, S);
}

// Round 10
// 4232.741 us; speedup vs baseline: 2.1275x; 1.1919x over previous
//
#include <hip/hip_runtime.h>
#include <math.h>

#define NR 8192      // NA == NT
#define DIM 256
#define NBLK 256     // fused-kernel blocks == column-partial chunks (1 per CU)
#define CROWS 32     // rows per chunk
#define RSC 2        // rows per sub-chunk
#define NSUB 16      // sub-chunks per chunk
// 10 * log2(e): converts distances directly into base-2 log domain
#define SCALE2 14.426950408889634f

// v_exp_f32 / v_log_f32 are base-2 natively — use them raw
__device__ __forceinline__ float fexp2(float x) {
#if __has_builtin(__builtin_amdgcn_exp2f)
    return __builtin_amdgcn_exp2f(x);
#else
    return exp2f(x);
#endif
}
__device__ __forceinline__ float flog2(float x) {
#if __has_builtin(__builtin_amdgcn_logf)
    return __builtin_amdgcn_logf(x);
#else
    return log2f(x);
#endif
}

// async global->LDS copy, 16 B per lane, no transit VGPRs.
// LDS dst is wave-uniform base; HW scatters lane i to base + i*16.
__device__ __forceinline__ void gl2lds16(const float* gp, float* lp) {
#if __has_builtin(__builtin_amdgcn_global_load_lds)
    __builtin_amdgcn_global_load_lds(
        (const __attribute__((address_space(1))) unsigned int*)gp,
        (__attribute__((address_space(3))) unsigned int*)lp, 16, 0, 0);
#else
    // fallback: synchronous copy (lane-contiguous, same layout)
    *(float4*)lp = *(const float4*)gp;   // note: callers pass lane-adjusted gp/lp in this mode
#endif
}

// base-2 online LSE combine
__device__ __forceinline__ void lse_comb2(float& m, float& s, float mo, float so) {
    float nm = fmaxf(m, mo);
    s = s * fexp2(m - nm) + so * fexp2(mo - nm);
    m = nm;
}

// grouped-4 online LSE update (1 tree-max + 1 correction exp per 4 values)
__device__ __forceinline__ void lse_upd4(float& m, float& s,
                                         float v0, float v1, float v2, float v3) {
    float m4 = fmaxf(fmaxf(v0, v1), fmaxf(v2, v3));
    float nm = fmaxf(m, m4);
    float e = fexp2(v0 - nm) + fexp2(v1 - nm) + fexp2(v2 - nm) + fexp2(v3 - nm);
    s = fmaf(s, fexp2(m - nm), e);
    m = nm;
}

// grouped-2 online LSE update
__device__ __forceinline__ void lse_upd2(float& m, float& s, float v0, float v1) {
    float m2 = fmaxf(v0, v1);
    float nm = fmaxf(m, m2);
    float e = fexp2(v0 - nm) + fexp2(v1 - nm);
    s = fmaf(s, fexp2(m - nm), e);
    m = nm;
}

// ---------------- init ----------------
__global__ void init_zero(float* __restrict__ g) {
    int t = blockIdx.x * 256 + threadIdx.x;
    if (t < NR) g[t] = 0.0f;
}

// ---------------- out[M,DIM] = A[M,DIM] @ W[DIM,DIM] + bias ----------------
__global__ __launch_bounds__(256) void gemm_qk(const float* __restrict__ A,
                                               const float* __restrict__ W,
                                               const float* __restrict__ bias,
                                               float* __restrict__ out) {
    __shared__ float As[16][68];
    __shared__ float Ws[16][68];
    const int t  = threadIdx.x;
    const int r0 = blockIdx.x * 64;
    const int c0 = blockIdx.y * 64;
    const int ty = t >> 4, tx = t & 15;
    const int arow = t >> 2;
    const int ak   = (t & 3) * 4;
    const int wrow = t >> 4;
    const int wcol = (t & 15) * 4;
    float acc[4][4] = {};
    for (int k0 = 0; k0 < DIM; k0 += 16) {
        float4 av = *(const float4*)(A + (size_t)(r0 + arow) * DIM + k0 + ak);
        float4 wv = *(const float4*)(W + (size_t)(k0 + wrow) * DIM + c0 + wcol);
        __syncthreads();
        As[ak + 0][arow] = av.x; As[ak + 1][arow] = av.y;
        As[ak + 2][arow] = av.z; As[ak + 3][arow] = av.w;
        *(float4*)&Ws[wrow][wcol] = wv;
        __syncthreads();
#pragma unroll
        for (int kk = 0; kk < 16; ++kk) {
            float4 a = *(const float4*)&As[kk][ty * 4];
            float4 b = *(const float4*)&Ws[kk][tx * 4];
            float aa[4] = {a.x, a.y, a.z, a.w};
            float bb[4] = {b.x, b.y, b.z, b.w};
#pragma unroll
            for (int i = 0; i < 4; ++i)
#pragma unroll
                for (int j = 0; j < 4; ++j)
                    acc[i][j] = fmaf(aa[i], bb[j], acc[i][j]);
        }
    }
#pragma unroll
    for (int i = 0; i < 4; ++i) {
        float4 o;
        o.x = acc[i][0] + bias[c0 + tx * 4 + 0];
        o.y = acc[i][1] + bias[c0 + tx * 4 + 1];
        o.z = acc[i][2] + bias[c0 + tx * 4 + 2];
        o.w = acc[i][3] + bias[c0 + tx * 4 + 3];
        *(float4*)(out + (size_t)(r0 + ty * 4 + i) * DIM + c0 + tx * 4) = o;
    }
}

// ---------------- row squared norms ----------------
__global__ __launch_bounds__(64) void row_norm(const float* __restrict__ x,
                                               float* __restrict__ out) {
    const int row = blockIdx.x, lane = threadIdx.x;
    float4 v = *(const float4*)(x + (size_t)row * DIM + lane * 4);
    float s = v.x * v.x + v.y * v.y + v.z * v.z + v.w * v.w;
#pragma unroll
    for (int off = 32; off > 0; off >>= 1) s += __shfl_xor(s, off);
    if (lane == 0) out[row] = s;
}

// ---------------- MLP logits: relu(A@W1+b1)@W2 + b2 ----------------
__global__ __launch_bounds__(128) void mlp_logits(const float* __restrict__ A,
                                                  const float* __restrict__ W1,
                                                  const float* __restrict__ b1,
                                                  const float* __restrict__ W2,
                                                  const float* __restrict__ b2,
                                                  float* __restrict__ logits) {
    __shared__ float ar[DIM];
    __shared__ float red[2];
    const int t = threadIdx.x;
    const int row = blockIdx.x;
    *(float2*)&ar[t * 2] = *(const float2*)(A + (size_t)row * DIM + t * 2);
    __syncthreads();
    float h = b1[t];
#pragma unroll 8
    for (int kk = 0; kk < DIM; ++kk) h = fmaf(ar[kk], W1[kk * 128 + t], h);
    float val = fmaxf(h, 0.0f) * W2[t];
#pragma unroll
    for (int off = 32; off > 0; off >>= 1) val += __shfl_xor(val, off);
    if ((t & 63) == 0) red[t >> 6] = val;
    __syncthreads();
    if (t == 0) logits[row] = red[0] + red[1] + b2[0];
}

// ---------------- softmax over 8192 logits -> log2(b + 1e-20) ----------------
__global__ __launch_bounds__(1024) void softmax_logb(const float* __restrict__ logits,
                                                     float* __restrict__ logb2) {
    __shared__ float redm[16], reds[16];
    const int t = threadIdx.x;
    float l[8];
    float m = -INFINITY;
#pragma unroll
    for (int i = 0; i < 8; ++i) { l[i] = logits[i * 1024 + t]; m = fmaxf(m, l[i]); }
#pragma unroll
    for (int off = 32; off > 0; off >>= 1) m = fmaxf(m, __shfl_xor(m, off));
    if ((t & 63) == 0) redm[t >> 6] = m;
    __syncthreads();
    if (t < 64) {
        float v = (t < 16) ? redm[t] : -INFINITY;
#pragma unroll
        for (int off = 8; off > 0; off >>= 1) v = fmaxf(v, __shfl_xor(v, off));
        if (t == 0) redm[0] = v;
    }
    __syncthreads();
    m = redm[0];
    float s = 0.0f;
#pragma unroll
    for (int i = 0; i < 8; ++i) s += __expf(l[i] - m);
#pragma unroll
    for (int off = 32; off > 0; off >>= 1) s += __shfl_xor(s, off);
    if ((t & 63) == 0) reds[t >> 6] = s;
    __syncthreads();
    if (t < 64) {
        float v = (t < 16) ? reds[t] : 0.0f;
#pragma unroll
        for (int off = 8; off > 0; off >>= 1) v += __shfl_xor(v, off);
        if (t == 0) reds[0] = v;
    }
    __syncthreads();
    s = reds[0];
    float invs = 1.0f / s;
#pragma unroll
    for (int i = 0; i < 8; ++i)
        logb2[i * 1024 + t] = log2f(__expf(l[i] - m) * invs + 1e-20f);
}

// ---------------- S[i][j] = log2e*10*(qn_i + kn_j - 2*q_i.k_j) ----------------
__global__ __launch_bounds__(256) void dist_kernel(const float* __restrict__ q,
                                                   const float* __restrict__ k,
                                                   const float* __restrict__ qn,
                                                   const float* __restrict__ kn,
                                                   float* __restrict__ S) {
    __shared__ float Qs[16][132];
    __shared__ float Ks[16][132];
    const int t  = threadIdx.x;
    const int r0 = blockIdx.y * 128;
    const int c0 = blockIdx.x * 128;
    const int lrow = t >> 1;
    const int lk   = (t & 1) * 8;
    const int wv   = t >> 6;
    const int lane = t & 63;
    const int ty8 = (wv >> 1) * 8 + (lane >> 3);
    const int tx8 = (wv & 1) * 8 + (lane & 7);
    float acc[8][8] = {};
    for (int k0 = 0; k0 < DIM; k0 += 16) {
        float4 qa = *(const float4*)(q + (size_t)(r0 + lrow) * DIM + k0 + lk);
        float4 qb = *(const float4*)(q + (size_t)(r0 + lrow) * DIM + k0 + lk + 4);
        float4 ka = *(const float4*)(k + (size_t)(c0 + lrow) * DIM + k0 + lk);
        float4 kb = *(const float4*)(k + (size_t)(c0 + lrow) * DIM + k0 + lk + 4);
        __syncthreads();
        Qs[lk + 0][lrow] = qa.x; Qs[lk + 1][lrow] = qa.y;
        Qs[lk + 2][lrow] = qa.z; Qs[lk + 3][lrow] = qa.w;
        Qs[lk + 4][lrow] = qb.x; Qs[lk + 5][lrow] = qb.y;
        Qs[lk + 6][lrow] = qb.z; Qs[lk + 7][lrow] = qb.w;
        Ks[lk + 0][lrow] = ka.x; Ks[lk + 1][lrow] = ka.y;
        Ks[lk + 2][lrow] = ka.z; Ks[lk + 3][lrow] = ka.w;
        Ks[lk + 4][lrow] = kb.x; Ks[lk + 5][lrow] = kb.y;
        Ks[lk + 6][lrow] = kb.z; Ks[lk + 7][lrow] = kb.w;
        __syncthreads();
#pragma unroll
        for (int kk = 0; kk < 16; ++kk) {
            float4 a0 = *(const float4*)&Qs[kk][ty8 * 8];
            float4 a1 = *(const float4*)&Qs[kk][ty8 * 8 + 4];
            float4 b0 = *(const float4*)&Ks[kk][tx8 * 8];
            float4 b1 = *(const float4*)&Ks[kk][tx8 * 8 + 4];
            float aa[8] = {a0.x, a0.y, a0.z, a0.w, a1.x, a1.y, a1.z, a1.w};
            float bb[8] = {b0.x, b0.y, b0.z, b0.w, b1.x, b1.y, b1.z, b1.w};
#pragma unroll
            for (int i = 0; i < 8; ++i)
#pragma unroll
                for (int j = 0; j < 8; ++j)
                    acc[i][j] = fmaf(aa[i], bb[j], acc[i][j]);
        }
    }
    float knv[8];
#pragma unroll
    for (int j = 0; j < 8; ++j) knv[j] = kn[c0 + tx8 * 8 + j];
#pragma unroll
    for (int i = 0; i < 8; ++i) {
        const int row = r0 + ty8 * 8 + i;
        const float qni = qn[row];
        float* outp = S + (size_t)row * NR + c0 + tx8 * 8;
        float4 o0, o1;
        o0.x = (qni + knv[0] - 2.0f * acc[i][0]) * SCALE2;
        o0.y = (qni + knv[1] - 2.0f * acc[i][1]) * SCALE2;
        o0.z = (qni + knv[2] - 2.0f * acc[i][2]) * SCALE2;
        o0.w = (qni + knv[3] - 2.0f * acc[i][3]) * SCALE2;
        o1.x = (qni + knv[4] - 2.0f * acc[i][4]) * SCALE2;
        o1.y = (qni + knv[5] - 2.0f * acc[i][5]) * SCALE2;
        o1.z = (qni + knv[6] - 2.0f * acc[i][6]) * SCALE2;
        o1.w = (qni + knv[7] - 2.0f * acc[i][7]) * SCALE2;
        *(float4*)outp = o0;
        *(float4*)(outp + 4) = o1;
    }
}

// ---------------- fused iteration: DMA-prefetched row LSE + column partials --------
// 256 blocks (1/CU) x 512 threads (8 waves), 32 rows per block, 2-row sub-chunks.
// Double-buffered LDS (2 x 64 KB). Sub-chunk k+1 is prefetched into the other
// buffer via global_load_lds (no transit VGPRs — the register-prefetch of R8
// spilled). Wave layout: rw = wv>>2 (row in sub-chunk), qt = wv&3 (row quarter);
// a wave's phase-1 LDS region is exactly the region its own DMA filled.
// Barrier A's vmcnt(0) drain doubles as the HBM wait, overlapped with phase 1.
__global__ __launch_bounds__(512, 2) void iter_fused(const float* __restrict__ S,
                                                     const float* __restrict__ g,
                                                     const float* __restrict__ logb2,
                                                     float* __restrict__ f,
                                                     float* __restrict__ pm) {
    __shared__ float buf[2][RSC][NR];   // 128 KB staging, double-buffered
    __shared__ float redm[8], reds[8];
    const int t = threadIdx.x;
    const int wv = t >> 6, lane = t & 63;
    const int chunk = blockIdx.x;
    const int r0 = chunk * CROWS;
    const int rw = wv >> 2;             // row (0..1) within sub-chunk
    const int qt = wv & 3;              // quarter of the row this wave handles
    const int qbase = qt * 2048;
    const int loff = lane * 4;

    // preload this wave's g quarter (constant within one launch): 8 float4
    float4 greg[8];
#pragma unroll
    for (int it = 0; it < 8; ++it)
        greg[it] = *(const float4*)(g + qbase + it * 256 + loff);

    // column accumulators: thread t owns cols {j*2048 + t*4 + c}
    float cm[4][4], cs[4][4];
#pragma unroll
    for (int j = 0; j < 4; ++j)
#pragma unroll
        for (int c = 0; c < 4; ++c) { cm[j][c] = -INFINITY; cs[j][c] = 0.0f; }

    // prologue: DMA sub-chunk 0 into buf[0]
    {
        const float* Sr = S + (size_t)(r0 + rw) * NR + qbase;
        float* ld = &buf[0][rw][qbase];
#pragma unroll
        for (int it = 0; it < 8; ++it)
#if __has_builtin(__builtin_amdgcn_global_load_lds)
            gl2lds16(Sr + it * 256 + loff, ld + it * 256);
#else
            gl2lds16(Sr + it * 256 + loff, ld + it * 256 + loff);
#endif
    }
    __syncthreads();   // drain prologue DMA

    for (int sc = 0; sc < NSUB; ++sc) {
        const int b = sc & 1;
        // ---- issue DMA for sub-chunk sc+1 into the other buffer ----
        if (sc + 1 < NSUB) {
            const float* Sn = S + (size_t)(r0 + (sc + 1) * RSC + rw) * NR + qbase;
            float* ld = &buf[b ^ 1][rw][qbase];
#pragma unroll
            for (int it = 0; it < 8; ++it)
#if __has_builtin(__builtin_amdgcn_global_load_lds)
                gl2lds16(Sn + it * 256 + loff, ld + it * 256);
#else
                gl2lds16(Sn + it * 256 + loff, ld + it * 256 + loff);
#endif
        }
        // ---- phase 1: row-LSE over this wave's quarter (LDS + g regs) ----
        float m = -INFINITY, s = 0.0f;
#pragma unroll
        for (int it = 0; it < 8; ++it) {
            float4 v = *(const float4*)&buf[b][rw][qbase + it * 256 + loff];
            float4 gv = greg[it];
            lse_upd4(m, s, v.x + gv.x, v.y + gv.y, v.z + gv.z, v.w + gv.w);
        }
#pragma unroll
        for (int off = 32; off > 0; off >>= 1) {
            float mo = __shfl_xor(m, off);
            float so = __shfl_xor(s, off);
            lse_comb2(m, s, mo, so);
        }
        if (lane == 0) { redm[wv] = m; reds[wv] = s; }
        __syncthreads();   // barrier A: red visible; vmcnt drain = HBM wait

        // ---- all threads: combine 4 quarter partials per row -> f0, f1 ----
        float fr[RSC];
#pragma unroll
        for (int r = 0; r < RSC; ++r) {
            float mm = redm[r * 4 + 0], ss = reds[r * 4 + 0];
            lse_comb2(mm, ss, redm[r * 4 + 1], reds[r * 4 + 1]);
            lse_comb2(mm, ss, redm[r * 4 + 2], reds[r * 4 + 2]);
            lse_comb2(mm, ss, redm[r * 4 + 3], reds[r * 4 + 3]);
            fr[r] = logb2[r0 + sc * RSC + r] - (mm + flog2(ss));
        }
        if (t < RSC) f[r0 + sc * RSC + t] = fr[t];

        // ---- phase 2: column partial-LSE over the 2 staged rows (LDS) ----
#pragma unroll
        for (int j = 0; j < 4; ++j) {
            const int c = j * 2048 + t * 4;
            float4 a = *(const float4*)&buf[b][0][c];
            float4 bb = *(const float4*)&buf[b][1][c];
            lse_upd2(cm[j][0], cs[j][0], a.x + fr[0], bb.x + fr[1]);
            lse_upd2(cm[j][1], cs[j][1], a.y + fr[0], bb.y + fr[1]);
            lse_upd2(cm[j][2], cs[j][2], a.z + fr[0], bb.z + fr[1]);
            lse_upd2(cm[j][3], cs[j][3], a.w + fr[0], bb.w + fr[1]);
        }
        __syncthreads();   // barrier B: buf[b] free for the DMA two iters out
    }
    // write column partials for this chunk as a single float L = m + log2(s)
#pragma unroll
    for (int j = 0; j < 4; ++j) {
        float4 L;
        L.x = cm[j][0] + flog2(cs[j][0]);
        L.y = cm[j][1] + flog2(cs[j][1]);
        L.z = cm[j][2] + flog2(cs[j][2]);
        L.w = cm[j][3] + flog2(cs[j][3]);
        *(float4*)&pm[(size_t)chunk * NR + j * 2048 + t * 4] = L;
    }
}

// ---------------- combine partials -> g (256 blocks, two-level LSE) ----------------
__global__ __launch_bounds__(256) void col_combine(const float* __restrict__ pm,
                                                   float* __restrict__ g,
                                                   float log_a2) {
    __shared__ float Lsh[8][32];
    const int cl = threadIdx.x & 31;       // column within block
    const int gp = threadIdx.x >> 5;       // chunk group (0..7)
    const int col = blockIdx.x * 32 + cl;
    float m = -INFINITY, s = 0.0f;
#pragma unroll
    for (int ch = gp * 32; ch < gp * 32 + 32; ch += 4) {
        float l0 = pm[(size_t)(ch + 0) * NR + col];
        float l1 = pm[(size_t)(ch + 1) * NR + col];
        float l2 = pm[(size_t)(ch + 2) * NR + col];
        float l3 = pm[(size_t)(ch + 3) * NR + col];
        lse_upd4(m, s, l0, l1, l2, l3);
    }
    Lsh[gp][cl] = m + flog2(s);
    __syncthreads();
    if (gp == 0) {
        float mm = -INFINITY, ss = 0.0f;
        lse_upd4(mm, ss, Lsh[0][cl], Lsh[1][cl], Lsh[2][cl], Lsh[3][cl]);
        lse_upd4(mm, ss, Lsh[4][cl], Lsh[5][cl], Lsh[6][cl], Lsh[7][cl]);
        g[col] = log_a2 - (mm + flog2(ss));
    }
}

// ---------------- T = exp2(f + S + g), in place; global sum == 1 analytically ------
// note: no __restrict__ on S/out — they alias (in-place)
__global__ __launch_bounds__(256) void write_pass(const float* S,
                                                  const float* __restrict__ f,
                                                  const float* __restrict__ g,
                                                  float* out) {
    const int wv = threadIdx.x >> 6, lane = threadIdx.x & 63;
    const int row = blockIdx.x * 4 + wv;
    const float fi = f[row];
    const float4* Sr = (const float4*)(S + (size_t)row * NR);
    const float4* gr = (const float4*)g;
    float4* Or = (float4*)(out + (size_t)row * NR);
#pragma unroll 4
    for (int it = 0; it < NR / 256; ++it) {
        const int idx = it * 64 + lane;
        float4 sv = Sr[idx];
        float4 gv = gr[idx];
        float4 o;
        o.x = fexp2(fi + sv.x + gv.x);
        o.y = fexp2(fi + sv.y + gv.y);
        o.z = fexp2(fi + sv.z + gv.z);
        o.w = fexp2(fi + sv.w + gv.w);
        Or[idx] = o;
    }
}

extern "C" void kernel_launch(void* const* d_in, const int* in_sizes, int n_in,
                              void* d_out, int out_size, void* d_ws, size_t ws_size,
                              hipStream_t stream) {
    (void)in_sizes; (void)n_in; (void)out_size; (void)ws_size;
    const float* A  = (const float*)d_in[0];
    const float* Tk = (const float*)d_in[1];
    const float* Wq = (const float*)d_in[2];
    const float* bq = (const float*)d_in[3];
    const float* Wk = (const float*)d_in[4];
    const float* bk = (const float*)d_in[5];
    const float* W1 = (const float*)d_in[6];
    const float* b1 = (const float*)d_in[7];
    const float* W2 = (const float*)d_in[8];
    const float* b2 = (const float*)d_in[9];
    float* S  = (float*)d_out;           // 8192x8192 base-2 log_K lives in d_out
    float* ws = (float*)d_ws;
    float* qn     = ws; ws += NR;
    float* kn     = ws; ws += NR;
    float* logb2  = ws; ws += NR;
    float* logits = ws; ws += NR;
    float* f      = ws; ws += NR;
    float* g      = ws; ws += NR;
    float* pm     = ws; ws += (size_t)NBLK * NR;   // 8 MB
    float* q      = ws; ws += (size_t)NR * DIM;    // 8 MB
    float* k      = ws; ws += (size_t)NR * DIM;    // 8 MB

    const float log_a2 = -13.0f; // log2(1/8192 + 1e-20)

    init_zero<<<32, 256, 0, stream>>>(g);
    gemm_qk<<<dim3(128, 4), 256, 0, stream>>>(A, Wq, bq, q);
    gemm_qk<<<dim3(128, 4), 256, 0, stream>>>(Tk, Wk, bk, k);
    row_norm<<<NR, 64, 0, stream>>>(q, qn);
    row_norm<<<NR, 64, 0, stream>>>(k, kn);
    mlp_logits<<<NR, 128, 0, stream>>>(A, W1, b1, W2, b2, logits);
    softmax_logb<<<1, 1024, 0, stream>>>(logits, logb2);
    dist_kernel<<<dim3(64, 64), 256, 0, stream>>>(q, k, qn, kn, S);
    for (int it = 0; it < 50; ++it) {
        iter_fused<<<NBLK, 512, 0, stream>>>(S, g, logb2, f, pm);
        col_combine<<<NR / 32, 256, 0, stream>>>(pm, g, log_a2);
    }
    write_pass<<<NR / 4, 256, 0, stream>>>(S, f, g, S);
}

// Round 11
// 4219.165 us; speedup vs baseline: 2.1344x; 1.0032x over previous
//
#include <hip/hip_runtime.h>
#include <math.h>

#define NR 8192      // NA == NT
#define DIM 256
#define NBLK 256     // fused-kernel blocks == column-partial chunks (1 per CU)
#define CROWS 32     // rows per chunk
#define RSC 2        // rows per sub-chunk
#define NSUB 16      // sub-chunks per chunk
// 10 * log2(e): converts distances directly into base-2 log domain
#define SCALE2 14.426950408889634f

// v_exp_f32 / v_log_f32 are base-2 natively — use them raw
__device__ __forceinline__ float fexp2(float x) {
#if __has_builtin(__builtin_amdgcn_exp2f)
    return __builtin_amdgcn_exp2f(x);
#else
    return exp2f(x);
#endif
}
__device__ __forceinline__ float flog2(float x) {
#if __has_builtin(__builtin_amdgcn_logf)
    return __builtin_amdgcn_logf(x);
#else
    return log2f(x);
#endif
}

// async global->LDS copy, 16 B per lane, no transit VGPRs.
// LDS dst is wave-uniform base; HW scatters lane i to base + i*16.
__device__ __forceinline__ void gl2lds16(const float* gp, float* lp) {
#if __has_builtin(__builtin_amdgcn_global_load_lds)
    __builtin_amdgcn_global_load_lds(
        (const __attribute__((address_space(1))) unsigned int*)gp,
        (__attribute__((address_space(3))) unsigned int*)lp, 16, 0, 0);
#else
    *(float4*)lp = *(const float4*)gp;   // fallback: callers pass lane-adjusted ptrs
#endif
}

// raw waits/barrier (m139/AITER pattern): barrier WITHOUT vmcnt(0) drain, so
// global_load_lds DMA stays in flight across it. "memory" clobber pins ordering.
__device__ __forceinline__ void wait_vm8()  { asm volatile("s_waitcnt vmcnt(8)" ::: "memory"); }
__device__ __forceinline__ void wait_vm0()  { asm volatile("s_waitcnt vmcnt(0)" ::: "memory"); }
__device__ __forceinline__ void bar_lgkm()  { asm volatile("s_waitcnt lgkmcnt(0)\ns_barrier" ::: "memory"); }

// base-2 online LSE combine
__device__ __forceinline__ void lse_comb2(float& m, float& s, float mo, float so) {
    float nm = fmaxf(m, mo);
    s = s * fexp2(m - nm) + so * fexp2(mo - nm);
    m = nm;
}

// grouped-4 online LSE update (1 tree-max + 1 correction exp per 4 values)
__device__ __forceinline__ void lse_upd4(float& m, float& s,
                                         float v0, float v1, float v2, float v3) {
    float m4 = fmaxf(fmaxf(v0, v1), fmaxf(v2, v3));
    float nm = fmaxf(m, m4);
    float e = fexp2(v0 - nm) + fexp2(v1 - nm) + fexp2(v2 - nm) + fexp2(v3 - nm);
    s = fmaf(s, fexp2(m - nm), e);
    m = nm;
}

// grouped-2 online LSE update
__device__ __forceinline__ void lse_upd2(float& m, float& s, float v0, float v1) {
    float m2 = fmaxf(v0, v1);
    float nm = fmaxf(m, m2);
    float e = fexp2(v0 - nm) + fexp2(v1 - nm);
    s = fmaf(s, fexp2(m - nm), e);
    m = nm;
}

// ---------------- init ----------------
__global__ void init_zero(float* __restrict__ g) {
    int t = blockIdx.x * 256 + threadIdx.x;
    if (t < NR) g[t] = 0.0f;
}

// ---------------- out[M,DIM] = A[M,DIM] @ W[DIM,DIM] + bias ----------------
__global__ __launch_bounds__(256) void gemm_qk(const float* __restrict__ A,
                                               const float* __restrict__ W,
                                               const float* __restrict__ bias,
                                               float* __restrict__ out) {
    __shared__ float As[16][68];
    __shared__ float Ws[16][68];
    const int t  = threadIdx.x;
    const int r0 = blockIdx.x * 64;
    const int c0 = blockIdx.y * 64;
    const int ty = t >> 4, tx = t & 15;
    const int arow = t >> 2;
    const int ak   = (t & 3) * 4;
    const int wrow = t >> 4;
    const int wcol = (t & 15) * 4;
    float acc[4][4] = {};
    for (int k0 = 0; k0 < DIM; k0 += 16) {
        float4 av = *(const float4*)(A + (size_t)(r0 + arow) * DIM + k0 + ak);
        float4 wv = *(const float4*)(W + (size_t)(k0 + wrow) * DIM + c0 + wcol);
        __syncthreads();
        As[ak + 0][arow] = av.x; As[ak + 1][arow] = av.y;
        As[ak + 2][arow] = av.z; As[ak + 3][arow] = av.w;
        *(float4*)&Ws[wrow][wcol] = wv;
        __syncthreads();
#pragma unroll
        for (int kk = 0; kk < 16; ++kk) {
            float4 a = *(const float4*)&As[kk][ty * 4];
            float4 b = *(const float4*)&Ws[kk][tx * 4];
            float aa[4] = {a.x, a.y, a.z, a.w};
            float bb[4] = {b.x, b.y, b.z, b.w};
#pragma unroll
            for (int i = 0; i < 4; ++i)
#pragma unroll
                for (int j = 0; j < 4; ++j)
                    acc[i][j] = fmaf(aa[i], bb[j], acc[i][j]);
        }
    }
#pragma unroll
    for (int i = 0; i < 4; ++i) {
        float4 o;
        o.x = acc[i][0] + bias[c0 + tx * 4 + 0];
        o.y = acc[i][1] + bias[c0 + tx * 4 + 1];
        o.z = acc[i][2] + bias[c0 + tx * 4 + 2];
        o.w = acc[i][3] + bias[c0 + tx * 4 + 3];
        *(float4*)(out + (size_t)(r0 + ty * 4 + i) * DIM + c0 + tx * 4) = o;
    }
}

// ---------------- row squared norms ----------------
__global__ __launch_bounds__(64) void row_norm(const float* __restrict__ x,
                                               float* __restrict__ out) {
    const int row = blockIdx.x, lane = threadIdx.x;
    float4 v = *(const float4*)(x + (size_t)row * DIM + lane * 4);
    float s = v.x * v.x + v.y * v.y + v.z * v.z + v.w * v.w;
#pragma unroll
    for (int off = 32; off > 0; off >>= 1) s += __shfl_xor(s, off);
    if (lane == 0) out[row] = s;
}

// ---------------- MLP logits: relu(A@W1+b1)@W2 + b2 ----------------
__global__ __launch_bounds__(128) void mlp_logits(const float* __restrict__ A,
                                                  const float* __restrict__ W1,
                                                  const float* __restrict__ b1,
                                                  const float* __restrict__ W2,
                                                  const float* __restrict__ b2,
                                                  float* __restrict__ logits) {
    __shared__ float ar[DIM];
    __shared__ float red[2];
    const int t = threadIdx.x;
    const int row = blockIdx.x;
    *(float2*)&ar[t * 2] = *(const float2*)(A + (size_t)row * DIM + t * 2);
    __syncthreads();
    float h = b1[t];
#pragma unroll 8
    for (int kk = 0; kk < DIM; ++kk) h = fmaf(ar[kk], W1[kk * 128 + t], h);
    float val = fmaxf(h, 0.0f) * W2[t];
#pragma unroll
    for (int off = 32; off > 0; off >>= 1) val += __shfl_xor(val, off);
    if ((t & 63) == 0) red[t >> 6] = val;
    __syncthreads();
    if (t == 0) logits[row] = red[0] + red[1] + b2[0];
}

// ---------------- softmax over 8192 logits -> log2(b + 1e-20) ----------------
__global__ __launch_bounds__(1024) void softmax_logb(const float* __restrict__ logits,
                                                     float* __restrict__ logb2) {
    __shared__ float redm[16], reds[16];
    const int t = threadIdx.x;
    float l[8];
    float m = -INFINITY;
#pragma unroll
    for (int i = 0; i < 8; ++i) { l[i] = logits[i * 1024 + t]; m = fmaxf(m, l[i]); }
#pragma unroll
    for (int off = 32; off > 0; off >>= 1) m = fmaxf(m, __shfl_xor(m, off));
    if ((t & 63) == 0) redm[t >> 6] = m;
    __syncthreads();
    if (t < 64) {
        float v = (t < 16) ? redm[t] : -INFINITY;
#pragma unroll
        for (int off = 8; off > 0; off >>= 1) v = fmaxf(v, __shfl_xor(v, off));
        if (t == 0) redm[0] = v;
    }
    __syncthreads();
    m = redm[0];
    float s = 0.0f;
#pragma unroll
    for (int i = 0; i < 8; ++i) s += __expf(l[i] - m);
#pragma unroll
    for (int off = 32; off > 0; off >>= 1) s += __shfl_xor(s, off);
    if ((t & 63) == 0) reds[t >> 6] = s;
    __syncthreads();
    if (t < 64) {
        float v = (t < 16) ? reds[t] : 0.0f;
#pragma unroll
        for (int off = 8; off > 0; off >>= 1) v += __shfl_xor(v, off);
        if (t == 0) reds[0] = v;
    }
    __syncthreads();
    s = reds[0];
    float invs = 1.0f / s;
#pragma unroll
    for (int i = 0; i < 8; ++i)
        logb2[i * 1024 + t] = log2f(__expf(l[i] - m) * invs + 1e-20f);
}

// ---------------- S[i][j] = log2e*10*(qn_i + kn_j - 2*q_i.k_j) ----------------
__global__ __launch_bounds__(256) void dist_kernel(const float* __restrict__ q,
                                                   const float* __restrict__ k,
                                                   const float* __restrict__ qn,
                                                   const float* __restrict__ kn,
                                                   float* __restrict__ S) {
    __shared__ float Qs[16][132];
    __shared__ float Ks[16][132];
    const int t  = threadIdx.x;
    const int r0 = blockIdx.y * 128;
    const int c0 = blockIdx.x * 128;
    const int lrow = t >> 1;
    const int lk   = (t & 1) * 8;
    const int wv   = t >> 6;
    const int lane = t & 63;
    const int ty8 = (wv >> 1) * 8 + (lane >> 3);
    const int tx8 = (wv & 1) * 8 + (lane & 7);
    float acc[8][8] = {};
    for (int k0 = 0; k0 < DIM; k0 += 16) {
        float4 qa = *(const float4*)(q + (size_t)(r0 + lrow) * DIM + k0 + lk);
        float4 qb = *(const float4*)(q + (size_t)(r0 + lrow) * DIM + k0 + lk + 4);
        float4 ka = *(const float4*)(k + (size_t)(c0 + lrow) * DIM + k0 + lk);
        float4 kb = *(const float4*)(k + (size_t)(c0 + lrow) * DIM + k0 + lk + 4);
        __syncthreads();
        Qs[lk + 0][lrow] = qa.x; Qs[lk + 1][lrow] = qa.y;
        Qs[lk + 2][lrow] = qa.z; Qs[lk + 3][lrow] = qa.w;
        Qs[lk + 4][lrow] = qb.x; Qs[lk + 5][lrow] = qb.y;
        Qs[lk + 6][lrow] = qb.z; Qs[lk + 7][lrow] = qb.w;
        Ks[lk + 0][lrow] = ka.x; Ks[lk + 1][lrow] = ka.y;
        Ks[lk + 2][lrow] = ka.z; Ks[lk + 3][lrow] = ka.w;
        Ks[lk + 4][lrow] = kb.x; Ks[lk + 5][lrow] = kb.y;
        Ks[lk + 6][lrow] = kb.z; Ks[lk + 7][lrow] = kb.w;
        __syncthreads();
#pragma unroll
        for (int kk = 0; kk < 16; ++kk) {
            float4 a0 = *(const float4*)&Qs[kk][ty8 * 8];
            float4 a1 = *(const float4*)&Qs[kk][ty8 * 8 + 4];
            float4 b0 = *(const float4*)&Ks[kk][tx8 * 8];
            float4 b1 = *(const float4*)&Ks[kk][tx8 * 8 + 4];
            float aa[8] = {a0.x, a0.y, a0.z, a0.w, a1.x, a1.y, a1.z, a1.w};
            float bb[8] = {b0.x, b0.y, b0.z, b0.w, b1.x, b1.y, b1.z, b1.w};
#pragma unroll
            for (int i = 0; i < 8; ++i)
#pragma unroll
                for (int j = 0; j < 8; ++j)
                    acc[i][j] = fmaf(aa[i], bb[j], acc[i][j]);
        }
    }
    float knv[8];
#pragma unroll
    for (int j = 0; j < 8; ++j) knv[j] = kn[c0 + tx8 * 8 + j];
#pragma unroll
    for (int i = 0; i < 8; ++i) {
        const int row = r0 + ty8 * 8 + i;
        const float qni = qn[row];
        float* outp = S + (size_t)row * NR + c0 + tx8 * 8;
        float4 o0, o1;
        o0.x = (qni + knv[0] - 2.0f * acc[i][0]) * SCALE2;
        o0.y = (qni + knv[1] - 2.0f * acc[i][1]) * SCALE2;
        o0.z = (qni + knv[2] - 2.0f * acc[i][2]) * SCALE2;
        o0.w = (qni + knv[3] - 2.0f * acc[i][3]) * SCALE2;
        o1.x = (qni + knv[4] - 2.0f * acc[i][4]) * SCALE2;
        o1.y = (qni + knv[5] - 2.0f * acc[i][5]) * SCALE2;
        o1.z = (qni + knv[6] - 2.0f * acc[i][6]) * SCALE2;
        o1.w = (qni + knv[7] - 2.0f * acc[i][7]) * SCALE2;
        *(float4*)outp = o0;
        *(float4*)(outp + 4) = o1;
    }
}

// ---------------- fused iteration: DMA-pipelined row LSE + column partials --------
// R10 structure, but barriers no longer drain vmcnt: raw `s_waitcnt lgkmcnt(0);
// s_barrier` (inline asm) + explicit `s_waitcnt vmcnt(8)` gating phase 1. DMA for
// sub-chunk k+1 is issued at the TOP of iter k and has the whole iteration
// (~2.8 µs) to stream, instead of 0.5 µs before a vmcnt(0) drain (R10's stall).
// Safety: every wave passes vmcnt(8) (its own DMA(k) complete) before barrier A,
// so all of buf[b] is complete before any wave's phase 2 reads it.
__global__ __launch_bounds__(512, 2) void iter_fused(const float* __restrict__ S,
                                                     const float* __restrict__ g,
                                                     const float* __restrict__ logb2,
                                                     float* __restrict__ f,
                                                     float* __restrict__ pm) {
    __shared__ float buf[2][RSC][NR];   // 128 KB staging, double-buffered
    __shared__ float redm[8], reds[8];
    const int t = threadIdx.x;
    const int wv = t >> 6, lane = t & 63;
    const int chunk = blockIdx.x;
    const int r0 = chunk * CROWS;
    const int rw = wv >> 2;             // row (0..1) within sub-chunk
    const int qt = wv & 3;              // quarter of the row this wave handles
    const int qbase = qt * 2048;
    const int loff = lane * 4;

    // preload this wave's g quarter (constant within one launch): 8 float4
    float4 greg[8];
#pragma unroll
    for (int it = 0; it < 8; ++it)
        greg[it] = *(const float4*)(g + qbase + it * 256 + loff);

    // column accumulators: thread t owns cols {j*2048 + t*4 + c}
    float cm[4][4], cs[4][4];
#pragma unroll
    for (int j = 0; j < 4; ++j)
#pragma unroll
        for (int c = 0; c < 4; ++c) { cm[j][c] = -INFINITY; cs[j][c] = 0.0f; }

    // prologue: DMA sub-chunk 0 into buf[0]
    {
        const float* Sr = S + (size_t)(r0 + rw) * NR + qbase;
        float* ld = &buf[0][rw][qbase];
#pragma unroll
        for (int it = 0; it < 8; ++it)
#if __has_builtin(__builtin_amdgcn_global_load_lds)
            gl2lds16(Sr + it * 256 + loff, ld + it * 256);
#else
            gl2lds16(Sr + it * 256 + loff, ld + it * 256 + loff);
#endif
    }

    for (int sc = 0; sc < NSUB; ++sc) {
        const int b = sc & 1;
        // ---- issue DMA for sub-chunk sc+1 into the other buffer (streams all iter) ----
        if (sc + 1 < NSUB) {
            const float* Sn = S + (size_t)(r0 + (sc + 1) * RSC + rw) * NR + qbase;
            float* ld = &buf[b ^ 1][rw][qbase];
#pragma unroll
            for (int it = 0; it < 8; ++it)
#if __has_builtin(__builtin_amdgcn_global_load_lds)
                gl2lds16(Sn + it * 256 + loff, ld + it * 256);
#else
                gl2lds16(Sn + it * 256 + loff, ld + it * 256 + loff);
#endif
            wait_vm8();   // wait the 8 OLDEST (DMA(sc) + stragglers); DMA(sc+1) stays in flight
        } else {
            wait_vm0();   // last sub-chunk: everything must be in
        }
        // ---- phase 1: row-LSE over this wave's quarter (LDS + g regs) ----
        float m = -INFINITY, s = 0.0f;
#pragma unroll
        for (int it = 0; it < 8; ++it) {
            float4 v = *(const float4*)&buf[b][rw][qbase + it * 256 + loff];
            float4 gv = greg[it];
            lse_upd4(m, s, v.x + gv.x, v.y + gv.y, v.z + gv.z, v.w + gv.w);
        }
#pragma unroll
        for (int off = 32; off > 0; off >>= 1) {
            float mo = __shfl_xor(m, off);
            float so = __shfl_xor(s, off);
            lse_comb2(m, s, mo, so);
        }
        if (lane == 0) { redm[wv] = m; reds[wv] = s; }
        bar_lgkm();   // barrier A: red + buf[b] ordered; DMA(sc+1) NOT drained

        // ---- all threads: combine 4 quarter partials per row -> f0, f1 ----
        float fr[RSC];
#pragma unroll
        for (int r = 0; r < RSC; ++r) {
            float mm = redm[r * 4 + 0], ss = reds[r * 4 + 0];
            lse_comb2(mm, ss, redm[r * 4 + 1], reds[r * 4 + 1]);
            lse_comb2(mm, ss, redm[r * 4 + 2], reds[r * 4 + 2]);
            lse_comb2(mm, ss, redm[r * 4 + 3], reds[r * 4 + 3]);
            fr[r] = logb2[r0 + sc * RSC + r] - (mm + flog2(ss));
        }
        if (t < RSC) f[r0 + sc * RSC + t] = fr[t];

        // ---- phase 2: column partial-LSE over the 2 staged rows (LDS) ----
#pragma unroll
        for (int j = 0; j < 4; ++j) {
            const int c = j * 2048 + t * 4;
            float4 a = *(const float4*)&buf[b][0][c];
            float4 bb = *(const float4*)&buf[b][1][c];
            lse_upd2(cm[j][0], cs[j][0], a.x + fr[0], bb.x + fr[1]);
            lse_upd2(cm[j][1], cs[j][1], a.y + fr[0], bb.y + fr[1]);
            lse_upd2(cm[j][2], cs[j][2], a.z + fr[0], bb.z + fr[1]);
            lse_upd2(cm[j][3], cs[j][3], a.w + fr[0], bb.w + fr[1]);
        }
        bar_lgkm();   // barrier B: buf[b] free for DMA(sc+2) next iteration
    }
    // write column partials for this chunk as a single float L = m + log2(s)
#pragma unroll
    for (int j = 0; j < 4; ++j) {
        float4 L;
        L.x = cm[j][0] + flog2(cs[j][0]);
        L.y = cm[j][1] + flog2(cs[j][1]);
        L.z = cm[j][2] + flog2(cs[j][2]);
        L.w = cm[j][3] + flog2(cs[j][3]);
        *(float4*)&pm[(size_t)chunk * NR + j * 2048 + t * 4] = L;
    }
}

// ---------------- combine partials -> g (256 blocks, two-level LSE) ----------------
__global__ __launch_bounds__(256) void col_combine(const float* __restrict__ pm,
                                                   float* __restrict__ g,
                                                   float log_a2) {
    __shared__ float Lsh[8][32];
    const int cl = threadIdx.x & 31;       // column within block
    const int gp = threadIdx.x >> 5;       // chunk group (0..7)
    const int col = blockIdx.x * 32 + cl;
    float m = -INFINITY, s = 0.0f;
#pragma unroll
    for (int ch = gp * 32; ch < gp * 32 + 32; ch += 4) {
        float l0 = pm[(size_t)(ch + 0) * NR + col];
        float l1 = pm[(size_t)(ch + 1) * NR + col];
        float l2 = pm[(size_t)(ch + 2) * NR + col];
        float l3 = pm[(size_t)(ch + 3) * NR + col];
        lse_upd4(m, s, l0, l1, l2, l3);
    }
    Lsh[gp][cl] = m + flog2(s);
    __syncthreads();
    if (gp == 0) {
        float mm = -INFINITY, ss = 0.0f;
        lse_upd4(mm, ss, Lsh[0][cl], Lsh[1][cl], Lsh[2][cl], Lsh[3][cl]);
        lse_upd4(mm, ss, Lsh[4][cl], Lsh[5][cl], Lsh[6][cl], Lsh[7][cl]);
        g[col] = log_a2 - (mm + flog2(ss));
    }
}

// ---------------- T = exp2(f + S + g), in place; global sum == 1 analytically ------
// note: no __restrict__ on S/out — they alias (in-place)
__global__ __launch_bounds__(256) void write_pass(const float* S,
                                                  const float* __restrict__ f,
                                                  const float* __restrict__ g,
                                                  float* out) {
    const int wv = threadIdx.x >> 6, lane = threadIdx.x & 63;
    const int row = blockIdx.x * 4 + wv;
    const float fi = f[row];
    const float4* Sr = (const float4*)(S + (size_t)row * NR);
    const float4* gr = (const float4*)g;
    float4* Or = (float4*)(out + (size_t)row * NR);
#pragma unroll 4
    for (int it = 0; it < NR / 256; ++it) {
        const int idx = it * 64 + lane;
        float4 sv = Sr[idx];
        float4 gv = gr[idx];
        float4 o;
        o.x = fexp2(fi + sv.x + gv.x);
        o.y = fexp2(fi + sv.y + gv.y);
        o.z = fexp2(fi + sv.z + gv.z);
        o.w = fexp2(fi + sv.w + gv.w);
        Or[idx] = o;
    }
}

extern "C" void kernel_launch(void* const* d_in, const int* in_sizes, int n_in,
                              void* d_out, int out_size, void* d_ws, size_t ws_size,
                              hipStream_t stream) {
    (void)in_sizes; (void)n_in; (void)out_size; (void)ws_size;
    const float* A  = (const float*)d_in[0];
    const float* Tk = (const float*)d_in[1];
    const float* Wq = (const float*)d_in[2];
    const float* bq = (const float*)d_in[3];
    const float* Wk = (const float*)d_in[4];
    const float* bk = (const float*)d_in[5];
    const float* W1 = (const float*)d_in[6];
    const float* b1 = (const float*)d_in[7];
    const float* W2 = (const float*)d_in[8];
    const float* b2 = (const float*)d_in[9];
    float* S  = (float*)d_out;           // 8192x8192 base-2 log_K lives in d_out
    float* ws = (float*)d_ws;
    float* qn     = ws; ws += NR;
    float* kn     = ws; ws += NR;
    float* logb2  = ws; ws += NR;
    float* logits = ws; ws += NR;
    float* f      = ws; ws += NR;
    float* g      = ws; ws += NR;
    float* pm     = ws; ws += (size_t)NBLK * NR;   // 8 MB
    float* q      = ws; ws += (size_t)NR * DIM;    // 8 MB
    float* k      = ws; ws += (size_t)NR * DIM;    // 8 MB

    const float log_a2 = -13.0f; // log2(1/8192 + 1e-20)

    init_zero<<<32, 256, 0, stream>>>(g);
    gemm_qk<<<dim3(128, 4), 256, 0, stream>>>(A, Wq, bq, q);
    gemm_qk<<<dim3(128, 4), 256, 0, stream>>>(Tk, Wk, bk, k);
    row_norm<<<NR, 64, 0, stream>>>(q, qn);
    row_norm<<<NR, 64, 0, stream>>>(k, kn);
    mlp_logits<<<NR, 128, 0, stream>>>(A, W1, b1, W2, b2, logits);
    softmax_logb<<<1, 1024, 0, stream>>>(logits, logb2);
    dist_kernel<<<dim3(64, 64), 256, 0, stream>>>(q, k, qn, kn, S);
    for (int it = 0; it < 50; ++it) {
        iter_fused<<<NBLK, 512, 0, stream>>>(S, g, logb2, f, pm);
        col_combine<<<NR / 32, 256, 0, stream>>>(pm, g, log_a2);
    }
    write_pass<<<NR / 4, 256, 0, stream>>>(S, f, g, S);
}

// Round 12
// 3621.272 us; speedup vs baseline: 2.4867x; 1.1651x over previous
//
#include <hip/hip_runtime.h>
#include <math.h>

#define NR 8192      // NA == NT
#define DIM 256
#define NBLK 512     // fused-kernel blocks == column-partial chunks (2 per CU)
#define CROWS 16     // rows per chunk
#define RSC 2        // rows per sub-chunk
#define NSUB 8       // sub-chunks per chunk
// 10 * log2(e): converts distances directly into base-2 log domain
#define SCALE2 14.426950408889634f

// v_exp_f32 / v_log_f32 are base-2 natively — use them raw
__device__ __forceinline__ float fexp2(float x) {
#if __has_builtin(__builtin_amdgcn_exp2f)
    return __builtin_amdgcn_exp2f(x);
#else
    return exp2f(x);
#endif
}
__device__ __forceinline__ float flog2(float x) {
#if __has_builtin(__builtin_amdgcn_logf)
    return __builtin_amdgcn_logf(x);
#else
    return log2f(x);
#endif
}

// async global->LDS copy, 16 B per lane, no transit VGPRs.
// LDS dst is wave-uniform base; HW scatters lane i to base + i*16.
__device__ __forceinline__ void gl2lds16(const float* gp, float* lp) {
#if __has_builtin(__builtin_amdgcn_global_load_lds)
    __builtin_amdgcn_global_load_lds(
        (const __attribute__((address_space(1))) unsigned int*)gp,
        (__attribute__((address_space(3))) unsigned int*)lp, 16, 0, 0);
#else
    *(float4*)lp = *(const float4*)gp;   // fallback: callers pass lane-adjusted ptrs
#endif
}

// raw waits/barrier: barrier WITHOUT vmcnt(0) drain; explicit vmcnt gate.
__device__ __forceinline__ void wait_vm0()  { asm volatile("s_waitcnt vmcnt(0)" ::: "memory"); }
__device__ __forceinline__ void bar_lgkm()  { asm volatile("s_waitcnt lgkmcnt(0)\ns_barrier" ::: "memory"); }

// base-2 online LSE combine
__device__ __forceinline__ void lse_comb2(float& m, float& s, float mo, float so) {
    float nm = fmaxf(m, mo);
    s = s * fexp2(m - nm) + so * fexp2(mo - nm);
    m = nm;
}

// grouped-4 online LSE update (1 tree-max + 1 correction exp per 4 values)
__device__ __forceinline__ void lse_upd4(float& m, float& s,
                                         float v0, float v1, float v2, float v3) {
    float m4 = fmaxf(fmaxf(v0, v1), fmaxf(v2, v3));
    float nm = fmaxf(m, m4);
    float e = fexp2(v0 - nm) + fexp2(v1 - nm) + fexp2(v2 - nm) + fexp2(v3 - nm);
    s = fmaf(s, fexp2(m - nm), e);
    m = nm;
}

// grouped-2 online LSE update
__device__ __forceinline__ void lse_upd2(float& m, float& s, float v0, float v1) {
    float m2 = fmaxf(v0, v1);
    float nm = fmaxf(m, m2);
    float e = fexp2(v0 - nm) + fexp2(v1 - nm);
    s = fmaf(s, fexp2(m - nm), e);
    m = nm;
}

// ---------------- init ----------------
__global__ void init_zero(float* __restrict__ g) {
    int t = blockIdx.x * 256 + threadIdx.x;
    if (t < NR) g[t] = 0.0f;
}

// ---------------- out[M,DIM] = A[M,DIM] @ W[DIM,DIM] + bias ----------------
__global__ __launch_bounds__(256) void gemm_qk(const float* __restrict__ A,
                                               const float* __restrict__ W,
                                               const float* __restrict__ bias,
                                               float* __restrict__ out) {
    __shared__ float As[16][68];
    __shared__ float Ws[16][68];
    const int t  = threadIdx.x;
    const int r0 = blockIdx.x * 64;
    const int c0 = blockIdx.y * 64;
    const int ty = t >> 4, tx = t & 15;
    const int arow = t >> 2;
    const int ak   = (t & 3) * 4;
    const int wrow = t >> 4;
    const int wcol = (t & 15) * 4;
    float acc[4][4] = {};
    for (int k0 = 0; k0 < DIM; k0 += 16) {
        float4 av = *(const float4*)(A + (size_t)(r0 + arow) * DIM + k0 + ak);
        float4 wv = *(const float4*)(W + (size_t)(k0 + wrow) * DIM + c0 + wcol);
        __syncthreads();
        As[ak + 0][arow] = av.x; As[ak + 1][arow] = av.y;
        As[ak + 2][arow] = av.z; As[ak + 3][arow] = av.w;
        *(float4*)&Ws[wrow][wcol] = wv;
        __syncthreads();
#pragma unroll
        for (int kk = 0; kk < 16; ++kk) {
            float4 a = *(const float4*)&As[kk][ty * 4];
            float4 b = *(const float4*)&Ws[kk][tx * 4];
            float aa[4] = {a.x, a.y, a.z, a.w};
            float bb[4] = {b.x, b.y, b.z, b.w};
#pragma unroll
            for (int i = 0; i < 4; ++i)
#pragma unroll
                for (int j = 0; j < 4; ++j)
                    acc[i][j] = fmaf(aa[i], bb[j], acc[i][j]);
        }
    }
#pragma unroll
    for (int i = 0; i < 4; ++i) {
        float4 o;
        o.x = acc[i][0] + bias[c0 + tx * 4 + 0];
        o.y = acc[i][1] + bias[c0 + tx * 4 + 1];
        o.z = acc[i][2] + bias[c0 + tx * 4 + 2];
        o.w = acc[i][3] + bias[c0 + tx * 4 + 3];
        *(float4*)(out + (size_t)(r0 + ty * 4 + i) * DIM + c0 + tx * 4) = o;
    }
}

// ---------------- row squared norms ----------------
__global__ __launch_bounds__(64) void row_norm(const float* __restrict__ x,
                                               float* __restrict__ out) {
    const int row = blockIdx.x, lane = threadIdx.x;
    float4 v = *(const float4*)(x + (size_t)row * DIM + lane * 4);
    float s = v.x * v.x + v.y * v.y + v.z * v.z + v.w * v.w;
#pragma unroll
    for (int off = 32; off > 0; off >>= 1) s += __shfl_xor(s, off);
    if (lane == 0) out[row] = s;
}

// ---------------- MLP logits: relu(A@W1+b1)@W2 + b2 ----------------
__global__ __launch_bounds__(128) void mlp_logits(const float* __restrict__ A,
                                                  const float* __restrict__ W1,
                                                  const float* __restrict__ b1,
                                                  const float* __restrict__ W2,
                                                  const float* __restrict__ b2,
                                                  float* __restrict__ logits) {
    __shared__ float ar[DIM];
    __shared__ float red[2];
    const int t = threadIdx.x;
    const int row = blockIdx.x;
    *(float2*)&ar[t * 2] = *(const float2*)(A + (size_t)row * DIM + t * 2);
    __syncthreads();
    float h = b1[t];
#pragma unroll 8
    for (int kk = 0; kk < DIM; ++kk) h = fmaf(ar[kk], W1[kk * 128 + t], h);
    float val = fmaxf(h, 0.0f) * W2[t];
#pragma unroll
    for (int off = 32; off > 0; off >>= 1) val += __shfl_xor(val, off);
    if ((t & 63) == 0) red[t >> 6] = val;
    __syncthreads();
    if (t == 0) logits[row] = red[0] + red[1] + b2[0];
}

// ---------------- softmax over 8192 logits -> log2(b + 1e-20) ----------------
__global__ __launch_bounds__(1024) void softmax_logb(const float* __restrict__ logits,
                                                     float* __restrict__ logb2) {
    __shared__ float redm[16], reds[16];
    const int t = threadIdx.x;
    float l[8];
    float m = -INFINITY;
#pragma unroll
    for (int i = 0; i < 8; ++i) { l[i] = logits[i * 1024 + t]; m = fmaxf(m, l[i]); }
#pragma unroll
    for (int off = 32; off > 0; off >>= 1) m = fmaxf(m, __shfl_xor(m, off));
    if ((t & 63) == 0) redm[t >> 6] = m;
    __syncthreads();
    if (t < 64) {
        float v = (t < 16) ? redm[t] : -INFINITY;
#pragma unroll
        for (int off = 8; off > 0; off >>= 1) v = fmaxf(v, __shfl_xor(v, off));
        if (t == 0) redm[0] = v;
    }
    __syncthreads();
    m = redm[0];
    float s = 0.0f;
#pragma unroll
    for (int i = 0; i < 8; ++i) s += __expf(l[i] - m);
#pragma unroll
    for (int off = 32; off > 0; off >>= 1) s += __shfl_xor(s, off);
    if ((t & 63) == 0) reds[t >> 6] = s;
    __syncthreads();
    if (t < 64) {
        float v = (t < 16) ? reds[t] : 0.0f;
#pragma unroll
        for (int off = 8; off > 0; off >>= 1) v += __shfl_xor(v, off);
        if (t == 0) reds[0] = v;
    }
    __syncthreads();
    s = reds[0];
    float invs = 1.0f / s;
#pragma unroll
    for (int i = 0; i < 8; ++i)
        logb2[i * 1024 + t] = log2f(__expf(l[i] - m) * invs + 1e-20f);
}

// ---------------- S[i][j] = log2e*10*(qn_i + kn_j - 2*q_i.k_j) ----------------
__global__ __launch_bounds__(256) void dist_kernel(const float* __restrict__ q,
                                                   const float* __restrict__ k,
                                                   const float* __restrict__ qn,
                                                   const float* __restrict__ kn,
                                                   float* __restrict__ S) {
    __shared__ float Qs[16][132];
    __shared__ float Ks[16][132];
    const int t  = threadIdx.x;
    const int r0 = blockIdx.y * 128;
    const int c0 = blockIdx.x * 128;
    const int lrow = t >> 1;
    const int lk   = (t & 1) * 8;
    const int wv   = t >> 6;
    const int lane = t & 63;
    const int ty8 = (wv >> 1) * 8 + (lane >> 3);
    const int tx8 = (wv & 1) * 8 + (lane & 7);
    float acc[8][8] = {};
    for (int k0 = 0; k0 < DIM; k0 += 16) {
        float4 qa = *(const float4*)(q + (size_t)(r0 + lrow) * DIM + k0 + lk);
        float4 qb = *(const float4*)(q + (size_t)(r0 + lrow) * DIM + k0 + lk + 4);
        float4 ka = *(const float4*)(k + (size_t)(c0 + lrow) * DIM + k0 + lk);
        float4 kb = *(const float4*)(k + (size_t)(c0 + lrow) * DIM + k0 + lk + 4);
        __syncthreads();
        Qs[lk + 0][lrow] = qa.x; Qs[lk + 1][lrow] = qa.y;
        Qs[lk + 2][lrow] = qa.z; Qs[lk + 3][lrow] = qa.w;
        Qs[lk + 4][lrow] = qb.x; Qs[lk + 5][lrow] = qb.y;
        Qs[lk + 6][lrow] = qb.z; Qs[lk + 7][lrow] = qb.w;
        Ks[lk + 0][lrow] = ka.x; Ks[lk + 1][lrow] = ka.y;
        Ks[lk + 2][lrow] = ka.z; Ks[lk + 3][lrow] = ka.w;
        Ks[lk + 4][lrow] = kb.x; Ks[lk + 5][lrow] = kb.y;
        Ks[lk + 6][lrow] = kb.z; Ks[lk + 7][lrow] = kb.w;
        __syncthreads();
#pragma unroll
        for (int kk = 0; kk < 16; ++kk) {
            float4 a0 = *(const float4*)&Qs[kk][ty8 * 8];
            float4 a1 = *(const float4*)&Qs[kk][ty8 * 8 + 4];
            float4 b0 = *(const float4*)&Ks[kk][tx8 * 8];
            float4 b1 = *(const float4*)&Ks[kk][tx8 * 8 + 4];
            float aa[8] = {a0.x, a0.y, a0.z, a0.w, a1.x, a1.y, a1.z, a1.w};
            float bb[8] = {b0.x, b0.y, b0.z, b0.w, b1.x, b1.y, b1.z, b1.w};
#pragma unroll
            for (int i = 0; i < 8; ++i)
#pragma unroll
                for (int j = 0; j < 8; ++j)
                    acc[i][j] = fmaf(aa[i], bb[j], acc[i][j]);
        }
    }
    float knv[8];
#pragma unroll
    for (int j = 0; j < 8; ++j) knv[j] = kn[c0 + tx8 * 8 + j];
#pragma unroll
    for (int i = 0; i < 8; ++i) {
        const int row = r0 + ty8 * 8 + i;
        const float qni = qn[row];
        float* outp = S + (size_t)row * NR + c0 + tx8 * 8;
        float4 o0, o1;
        o0.x = (qni + knv[0] - 2.0f * acc[i][0]) * SCALE2;
        o0.y = (qni + knv[1] - 2.0f * acc[i][1]) * SCALE2;
        o0.z = (qni + knv[2] - 2.0f * acc[i][2]) * SCALE2;
        o0.w = (qni + knv[3] - 2.0f * acc[i][3]) * SCALE2;
        o1.x = (qni + knv[4] - 2.0f * acc[i][4]) * SCALE2;
        o1.y = (qni + knv[5] - 2.0f * acc[i][5]) * SCALE2;
        o1.z = (qni + knv[6] - 2.0f * acc[i][6]) * SCALE2;
        o1.w = (qni + knv[7] - 2.0f * acc[i][7]) * SCALE2;
        *(float4*)outp = o0;
        *(float4*)(outp + 4) = o1;
    }
}

// ---------------- fused iteration: DMA staging + 2 blocks/CU overlap ----------------
// 512 blocks (2/CU) x 512 threads, 16 rows per block, 2-row sub-chunks, single
// 64 KB LDS buffer. Within a block the DMA wait is exposed — but the sibling
// block on the same CU is in its compute phase during that window, so CU-level
// HBM stays busy. Overlap via occupancy (the only pipelining that has worked on
// this structure: R6/R8/R11 intra-block attempts all failed). DMA staging keeps
// the register footprint ~100 VGPRs so __launch_bounds__(512,4) holds w/o spill.
__global__ __launch_bounds__(512, 4) void iter_fused(const float* __restrict__ S,
                                                     const float* __restrict__ g,
                                                     const float* __restrict__ logb2,
                                                     float* __restrict__ f,
                                                     float* __restrict__ pm) {
    __shared__ float buf[RSC][NR];      // 64 KB staging (single buffer)
    __shared__ float redm[8], reds[8];
    const int t = threadIdx.x;
    const int wv = t >> 6, lane = t & 63;
    const int chunk = blockIdx.x;
    const int r0 = chunk * CROWS;
    const int rw = wv >> 2;             // row (0..1) within sub-chunk
    const int qt = wv & 3;              // quarter of the row this wave handles
    const int qbase = qt * 2048;
    const int loff = lane * 4;

    // preload this wave's g quarter (constant within one launch): 8 float4
    float4 greg[8];
#pragma unroll
    for (int it = 0; it < 8; ++it)
        greg[it] = *(const float4*)(g + qbase + it * 256 + loff);

    // column accumulators: thread t owns cols {j*2048 + t*4 + c}
    float cm[4][4], cs[4][4];
#pragma unroll
    for (int j = 0; j < 4; ++j)
#pragma unroll
        for (int c = 0; c < 4; ++c) { cm[j][c] = -INFINITY; cs[j][c] = 0.0f; }

    // prologue: DMA sub-chunk 0
    {
        const float* Sr = S + (size_t)(r0 + rw) * NR + qbase;
        float* ld = &buf[rw][qbase];
#pragma unroll
        for (int it = 0; it < 8; ++it)
#if __has_builtin(__builtin_amdgcn_global_load_lds)
            gl2lds16(Sr + it * 256 + loff, ld + it * 256);
#else
            gl2lds16(Sr + it * 256 + loff, ld + it * 256 + loff);
#endif
    }

    for (int sc = 0; sc < NSUB; ++sc) {
        wait_vm0();   // own DMA(sc) (and greg/f stragglers) complete
        // ---- phase 1: row-LSE over this wave's quarter (LDS + g regs) ----
        float m = -INFINITY, s = 0.0f;
#pragma unroll
        for (int it = 0; it < 8; ++it) {
            float4 v = *(const float4*)&buf[rw][qbase + it * 256 + loff];
            float4 gv = greg[it];
            lse_upd4(m, s, v.x + gv.x, v.y + gv.y, v.z + gv.z, v.w + gv.w);
        }
#pragma unroll
        for (int off = 32; off > 0; off >>= 1) {
            float mo = __shfl_xor(m, off);
            float so = __shfl_xor(s, off);
            lse_comb2(m, s, mo, so);
        }
        if (lane == 0) { redm[wv] = m; reds[wv] = s; }
        bar_lgkm();   // barrier A: all DMA(sc) complete block-wide; red visible

        // ---- all threads: combine 4 quarter partials per row -> f0, f1 ----
        float fr[RSC];
#pragma unroll
        for (int r = 0; r < RSC; ++r) {
            float mm = redm[r * 4 + 0], ss = reds[r * 4 + 0];
            lse_comb2(mm, ss, redm[r * 4 + 1], reds[r * 4 + 1]);
            lse_comb2(mm, ss, redm[r * 4 + 2], reds[r * 4 + 2]);
            lse_comb2(mm, ss, redm[r * 4 + 3], reds[r * 4 + 3]);
            fr[r] = logb2[r0 + sc * RSC + r] - (mm + flog2(ss));
        }
        if (t < RSC) f[r0 + sc * RSC + t] = fr[t];

        // ---- phase 2: column partial-LSE over the 2 staged rows (LDS) ----
#pragma unroll
        for (int j = 0; j < 4; ++j) {
            const int c = j * 2048 + t * 4;
            float4 a = *(const float4*)&buf[0][c];
            float4 bb = *(const float4*)&buf[1][c];
            lse_upd2(cm[j][0], cs[j][0], a.x + fr[0], bb.x + fr[1]);
            lse_upd2(cm[j][1], cs[j][1], a.y + fr[0], bb.y + fr[1]);
            lse_upd2(cm[j][2], cs[j][2], a.z + fr[0], bb.z + fr[1]);
            lse_upd2(cm[j][3], cs[j][3], a.w + fr[0], bb.w + fr[1]);
        }
        bar_lgkm();   // barrier B: every wave done reading buf

        // ---- issue DMA for sub-chunk sc+1 (safe: all reads of buf finished) ----
        if (sc + 1 < NSUB) {
            const float* Sn = S + (size_t)(r0 + (sc + 1) * RSC + rw) * NR + qbase;
            float* ld = &buf[rw][qbase];
#pragma unroll
            for (int it = 0; it < 8; ++it)
#if __has_builtin(__builtin_amdgcn_global_load_lds)
                gl2lds16(Sn + it * 256 + loff, ld + it * 256);
#else
                gl2lds16(Sn + it * 256 + loff, ld + it * 256 + loff);
#endif
        }
    }
    // write column partials for this chunk as a single float L = m + log2(s)
#pragma unroll
    for (int j = 0; j < 4; ++j) {
        float4 L;
        L.x = cm[j][0] + flog2(cs[j][0]);
        L.y = cm[j][1] + flog2(cs[j][1]);
        L.z = cm[j][2] + flog2(cs[j][2]);
        L.w = cm[j][3] + flog2(cs[j][3]);
        *(float4*)&pm[(size_t)chunk * NR + j * 2048 + t * 4] = L;
    }
}

// ---------------- combine partials -> g (256 blocks, two-level LSE) ----------------
__global__ __launch_bounds__(256) void col_combine(const float* __restrict__ pm,
                                                   float* __restrict__ g,
                                                   float log_a2) {
    __shared__ float Lsh[8][32];
    const int cl = threadIdx.x & 31;       // column within block
    const int gp = threadIdx.x >> 5;       // chunk group (0..7), 64 chunks each
    const int col = blockIdx.x * 32 + cl;
    float m = -INFINITY, s = 0.0f;
#pragma unroll
    for (int ch = gp * 64; ch < gp * 64 + 64; ch += 4) {
        float l0 = pm[(size_t)(ch + 0) * NR + col];
        float l1 = pm[(size_t)(ch + 1) * NR + col];
        float l2 = pm[(size_t)(ch + 2) * NR + col];
        float l3 = pm[(size_t)(ch + 3) * NR + col];
        lse_upd4(m, s, l0, l1, l2, l3);
    }
    Lsh[gp][cl] = m + flog2(s);
    __syncthreads();
    if (gp == 0) {
        float mm = -INFINITY, ss = 0.0f;
        lse_upd4(mm, ss, Lsh[0][cl], Lsh[1][cl], Lsh[2][cl], Lsh[3][cl]);
        lse_upd4(mm, ss, Lsh[4][cl], Lsh[5][cl], Lsh[6][cl], Lsh[7][cl]);
        g[col] = log_a2 - (mm + flog2(ss));
    }
}

// ---------------- T = exp2(f + S + g), in place; global sum == 1 analytically ------
// note: no __restrict__ on S/out — they alias (in-place)
__global__ __launch_bounds__(256) void write_pass(const float* S,
                                                  const float* __restrict__ f,
                                                  const float* __restrict__ g,
                                                  float* out) {
    const int wv = threadIdx.x >> 6, lane = threadIdx.x & 63;
    const int row = blockIdx.x * 4 + wv;
    const float fi = f[row];
    const float4* Sr = (const float4*)(S + (size_t)row * NR);
    const float4* gr = (const float4*)g;
    float4* Or = (float4*)(out + (size_t)row * NR);
#pragma unroll 4
    for (int it = 0; it < NR / 256; ++it) {
        const int idx = it * 64 + lane;
        float4 sv = Sr[idx];
        float4 gv = gr[idx];
        float4 o;
        o.x = fexp2(fi + sv.x + gv.x);
        o.y = fexp2(fi + sv.y + gv.y);
        o.z = fexp2(fi + sv.z + gv.z);
        o.w = fexp2(fi + sv.w + gv.w);
        Or[idx] = o;
    }
}

extern "C" void kernel_launch(void* const* d_in, const int* in_sizes, int n_in,
                              void* d_out, int out_size, void* d_ws, size_t ws_size,
                              hipStream_t stream) {
    (void)in_sizes; (void)n_in; (void)out_size; (void)ws_size;
    const float* A  = (const float*)d_in[0];
    const float* Tk = (const float*)d_in[1];
    const float* Wq = (const float*)d_in[2];
    const float* bq = (const float*)d_in[3];
    const float* Wk = (const float*)d_in[4];
    const float* bk = (const float*)d_in[5];
    const float* W1 = (const float*)d_in[6];
    const float* b1 = (const float*)d_in[7];
    const float* W2 = (const float*)d_in[8];
    const float* b2 = (const float*)d_in[9];
    float* S  = (float*)d_out;           // 8192x8192 base-2 log_K lives in d_out
    float* ws = (float*)d_ws;
    float* qn     = ws; ws += NR;
    float* kn     = ws; ws += NR;
    float* logb2  = ws; ws += NR;
    float* logits = ws; ws += NR;
    float* f      = ws; ws += NR;
    float* g      = ws; ws += NR;
    float* pm     = ws; ws += (size_t)NBLK * NR;   // 16 MB
    float* q      = ws; ws += (size_t)NR * DIM;    // 8 MB
    float* k      = ws; ws += (size_t)NR * DIM;    // 8 MB

    const float log_a2 = -13.0f; // log2(1/8192 + 1e-20)

    init_zero<<<32, 256, 0, stream>>>(g);
    gemm_qk<<<dim3(128, 4), 256, 0, stream>>>(A, Wq, bq, q);
    gemm_qk<<<dim3(128, 4), 256, 0, stream>>>(Tk, Wk, bk, k);
    row_norm<<<NR, 64, 0, stream>>>(q, qn);
    row_norm<<<NR, 64, 0, stream>>>(k, kn);
    mlp_logits<<<NR, 128, 0, stream>>>(A, W1, b1, W2, b2, logits);
    softmax_logb<<<1, 1024, 0, stream>>>(logits, logb2);
    dist_kernel<<<dim3(64, 64), 256, 0, stream>>>(q, k, qn, kn, S);
    for (int it = 0; it < 50; ++it) {
        iter_fused<<<NBLK, 512, 0, stream>>>(S, g, logb2, f, pm);
        col_combine<<<NR / 32, 256, 0, stream>>>(pm, g, log_a2);
    }
    write_pass<<<NR / 4, 256, 0, stream>>>(S, f, g, S);
}

// Round 13
// 3438.234 us; speedup vs baseline: 2.6191x; 1.0532x over previous
//
#include <hip/hip_runtime.h>
#include <math.h>

#define NR 8192      // NA == NT
#define DIM 256
#define NBLK 512     // fused-kernel blocks == column-partial chunks (2 per CU)
#define CROWS 16     // rows per chunk
#define RSC 2        // rows per sub-chunk
#define NSUB 8       // sub-chunks per chunk
// 10 * log2(e): converts distances directly into base-2 log domain
#define SCALE2 14.426950408889634f

typedef unsigned short ushort_t;
typedef __attribute__((ext_vector_type(8))) short bfrag;   // 8 bf16 (4 VGPRs)
typedef __attribute__((ext_vector_type(4))) float facc;    // 4 fp32 acc

// v_exp_f32 / v_log_f32 are base-2 natively — use them raw
__device__ __forceinline__ float fexp2(float x) {
#if __has_builtin(__builtin_amdgcn_exp2f)
    return __builtin_amdgcn_exp2f(x);
#else
    return exp2f(x);
#endif
}
__device__ __forceinline__ float flog2(float x) {
#if __has_builtin(__builtin_amdgcn_logf)
    return __builtin_amdgcn_logf(x);
#else
    return log2f(x);
#endif
}

// async global->LDS copy, 16 B per lane, no transit VGPRs.
__device__ __forceinline__ void gl2lds16(const float* gp, float* lp) {
#if __has_builtin(__builtin_amdgcn_global_load_lds)
    __builtin_amdgcn_global_load_lds(
        (const __attribute__((address_space(1))) unsigned int*)gp,
        (__attribute__((address_space(3))) unsigned int*)lp, 16, 0, 0);
#else
    *(float4*)lp = *(const float4*)gp;   // fallback: callers pass lane-adjusted ptrs
#endif
}

// raw waits/barrier: barrier WITHOUT vmcnt(0) drain; explicit vmcnt gate.
__device__ __forceinline__ void wait_vm0()  { asm volatile("s_waitcnt vmcnt(0)" ::: "memory"); }
__device__ __forceinline__ void bar_lgkm()  { asm volatile("s_waitcnt lgkmcnt(0)\ns_barrier" ::: "memory"); }

// base-2 online LSE combine
__device__ __forceinline__ void lse_comb2(float& m, float& s, float mo, float so) {
    float nm = fmaxf(m, mo);
    s = s * fexp2(m - nm) + so * fexp2(mo - nm);
    m = nm;
}

// grouped-4 online LSE update (1 tree-max + 1 correction exp per 4 values)
__device__ __forceinline__ void lse_upd4(float& m, float& s,
                                         float v0, float v1, float v2, float v3) {
    float m4 = fmaxf(fmaxf(v0, v1), fmaxf(v2, v3));
    float nm = fmaxf(m, m4);
    float e = fexp2(v0 - nm) + fexp2(v1 - nm) + fexp2(v2 - nm) + fexp2(v3 - nm);
    s = fmaf(s, fexp2(m - nm), e);
    m = nm;
}

// grouped-2 online LSE update
__device__ __forceinline__ void lse_upd2(float& m, float& s, float v0, float v1) {
    float m2 = fmaxf(v0, v1);
    float nm = fmaxf(m, m2);
    float e = fexp2(v0 - nm) + fexp2(v1 - nm);
    s = fmaf(s, fexp2(m - nm), e);
    m = nm;
}

// RNE float -> bf16 bits (manual: deterministic, no API variance)
__device__ __forceinline__ ushort_t f2bf(float x) {
    unsigned u = __float_as_uint(x);
    u += 0x7FFFu + ((u >> 16) & 1u);
    return (ushort_t)(u >> 16);
}
__device__ __forceinline__ float bf2f(ushort_t b) {
    return __uint_as_float(((unsigned)b) << 16);
}

// ---------------- init ----------------
__global__ void init_zero(float* __restrict__ g) {
    int t = blockIdx.x * 256 + threadIdx.x;
    if (t < NR) g[t] = 0.0f;
}

// ---------------- out[M,DIM] = A[M,DIM] @ W[DIM,DIM] + bias ----------------
__global__ __launch_bounds__(256) void gemm_qk(const float* __restrict__ A,
                                               const float* __restrict__ W,
                                               const float* __restrict__ bias,
                                               float* __restrict__ out) {
    __shared__ float As[16][68];
    __shared__ float Ws[16][68];
    const int t  = threadIdx.x;
    const int r0 = blockIdx.x * 64;
    const int c0 = blockIdx.y * 64;
    const int ty = t >> 4, tx = t & 15;
    const int arow = t >> 2;
    const int ak   = (t & 3) * 4;
    const int wrow = t >> 4;
    const int wcol = (t & 15) * 4;
    float acc[4][4] = {};
    for (int k0 = 0; k0 < DIM; k0 += 16) {
        float4 av = *(const float4*)(A + (size_t)(r0 + arow) * DIM + k0 + ak);
        float4 wv = *(const float4*)(W + (size_t)(k0 + wrow) * DIM + c0 + wcol);
        __syncthreads();
        As[ak + 0][arow] = av.x; As[ak + 1][arow] = av.y;
        As[ak + 2][arow] = av.z; As[ak + 3][arow] = av.w;
        *(float4*)&Ws[wrow][wcol] = wv;
        __syncthreads();
#pragma unroll
        for (int kk = 0; kk < 16; ++kk) {
            float4 a = *(const float4*)&As[kk][ty * 4];
            float4 b = *(const float4*)&Ws[kk][tx * 4];
            float aa[4] = {a.x, a.y, a.z, a.w};
            float bb[4] = {b.x, b.y, b.z, b.w};
#pragma unroll
            for (int i = 0; i < 4; ++i)
#pragma unroll
                for (int j = 0; j < 4; ++j)
                    acc[i][j] = fmaf(aa[i], bb[j], acc[i][j]);
        }
    }
#pragma unroll
    for (int i = 0; i < 4; ++i) {
        float4 o;
        o.x = acc[i][0] + bias[c0 + tx * 4 + 0];
        o.y = acc[i][1] + bias[c0 + tx * 4 + 1];
        o.z = acc[i][2] + bias[c0 + tx * 4 + 2];
        o.w = acc[i][3] + bias[c0 + tx * 4 + 3];
        *(float4*)(out + (size_t)(r0 + ty * 4 + i) * DIM + c0 + tx * 4) = o;
    }
}

// ---------------- row squared norms ----------------
__global__ __launch_bounds__(64) void row_norm(const float* __restrict__ x,
                                               float* __restrict__ out) {
    const int row = blockIdx.x, lane = threadIdx.x;
    float4 v = *(const float4*)(x + (size_t)row * DIM + lane * 4);
    float s = v.x * v.x + v.y * v.y + v.z * v.z + v.w * v.w;
#pragma unroll
    for (int off = 32; off > 0; off >>= 1) s += __shfl_xor(s, off);
    if (lane == 0) out[row] = s;
}

// ---------------- split fp32 -> bf16 hi + bf16 lo (lo = bf16(x - hi)) ----------------
__global__ __launch_bounds__(256) void split_bf16(const float* __restrict__ x,
                                                  ushort_t* __restrict__ hi,
                                                  ushort_t* __restrict__ lo) {
    const int idx = (blockIdx.x * 256 + threadIdx.x) * 4;
    float4 v = *(const float4*)(x + idx);
    ushort_t h0 = f2bf(v.x), h1 = f2bf(v.y), h2 = f2bf(v.z), h3 = f2bf(v.w);
    ushort4 hv = make_ushort4(h0, h1, h2, h3);
    ushort4 lv = make_ushort4(f2bf(v.x - bf2f(h0)), f2bf(v.y - bf2f(h1)),
                              f2bf(v.z - bf2f(h2)), f2bf(v.w - bf2f(h3)));
    *(ushort4*)(hi + idx) = hv;
    *(ushort4*)(lo + idx) = lv;
}

// ---------------- S = SCALE2*(qn_i + kn_j - 2*q_i.k_j) via split-bf16 MFMA ----------
// 4096 blocks x 256 threads (4 waves, 2x2 of 64x64). mfma_f32_16x16x32_bf16:
// A[m=lane&15][k=quad*8+j], B[n=lane&15][k=quad*8+j] -> contiguous 16 B/lane loads
// straight from global (row-major bf16, L2/L3-served). Full 4-product split
// (hh+hl+lh+ll): per-element error <= 2^-19 — adds ~4e-4 exponent error,
// negligible vs the ~1e-2 LSE accumulation error. C/D: col=lane&15,
// row=quad*4+reg (m89-verified).
__global__ __launch_bounds__(256) void dist_mfma(const ushort_t* __restrict__ qh,
                                                 const ushort_t* __restrict__ ql,
                                                 const ushort_t* __restrict__ kh,
                                                 const ushort_t* __restrict__ kl,
                                                 const float* __restrict__ qn,
                                                 const float* __restrict__ kn,
                                                 float* __restrict__ S) {
    const int t = threadIdx.x;
    const int wv = t >> 6, lane = t & 63;
    const int r0 = blockIdx.y * 128 + (wv >> 1) * 64;
    const int c0 = blockIdx.x * 128 + (wv & 1) * 64;
    const int fr = lane & 15;       // row (A) / col (B) within 16x16 tile
    const int fq = lane >> 4;       // quad -> k-subrange / C-row group
    facc acc[4][4];
#pragma unroll
    for (int i = 0; i < 4; ++i)
#pragma unroll
        for (int j = 0; j < 4; ++j) acc[i][j] = (facc){0.f, 0.f, 0.f, 0.f};

    for (int k0 = 0; k0 < DIM; k0 += 32) {
        const int ks = k0 + fq * 8;
        bfrag ah[4], al[4], bh[4], bl[4];
#pragma unroll
        for (int mi = 0; mi < 4; ++mi) {
            const size_t ao = (size_t)(r0 + mi * 16 + fr) * DIM + ks;
            ah[mi] = *(const bfrag*)(qh + ao);
            al[mi] = *(const bfrag*)(ql + ao);
        }
#pragma unroll
        for (int ni = 0; ni < 4; ++ni) {
            const size_t bo = (size_t)(c0 + ni * 16 + fr) * DIM + ks;
            bh[ni] = *(const bfrag*)(kh + bo);
            bl[ni] = *(const bfrag*)(kl + bo);
        }
#pragma unroll
        for (int mi = 0; mi < 4; ++mi)
#pragma unroll
            for (int ni = 0; ni < 4; ++ni) {
                acc[mi][ni] = __builtin_amdgcn_mfma_f32_16x16x32_bf16(ah[mi], bh[ni], acc[mi][ni], 0, 0, 0);
                acc[mi][ni] = __builtin_amdgcn_mfma_f32_16x16x32_bf16(ah[mi], bl[ni], acc[mi][ni], 0, 0, 0);
                acc[mi][ni] = __builtin_amdgcn_mfma_f32_16x16x32_bf16(al[mi], bh[ni], acc[mi][ni], 0, 0, 0);
                acc[mi][ni] = __builtin_amdgcn_mfma_f32_16x16x32_bf16(al[mi], bl[ni], acc[mi][ni], 0, 0, 0);
            }
    }
    // epilogue: S[row][col] = (qn + kn - 2*dot) * SCALE2
#pragma unroll
    for (int mi = 0; mi < 4; ++mi) {
        float qnr[4];
#pragma unroll
        for (int r = 0; r < 4; ++r) qnr[r] = qn[r0 + mi * 16 + fq * 4 + r];
#pragma unroll
        for (int ni = 0; ni < 4; ++ni) {
            const int col = c0 + ni * 16 + fr;
            const float knc = kn[col];
#pragma unroll
            for (int r = 0; r < 4; ++r) {
                const int row = r0 + mi * 16 + fq * 4 + r;
                S[(size_t)row * NR + col] = (qnr[r] + knc - 2.0f * acc[mi][ni][r]) * SCALE2;
            }
        }
    }
}

// ---------------- MLP logits: relu(A@W1+b1)@W2 + b2 ----------------
__global__ __launch_bounds__(128) void mlp_logits(const float* __restrict__ A,
                                                  const float* __restrict__ W1,
                                                  const float* __restrict__ b1,
                                                  const float* __restrict__ W2,
                                                  const float* __restrict__ b2,
                                                  float* __restrict__ logits) {
    __shared__ float ar[DIM];
    __shared__ float red[2];
    const int t = threadIdx.x;
    const int row = blockIdx.x;
    *(float2*)&ar[t * 2] = *(const float2*)(A + (size_t)row * DIM + t * 2);
    __syncthreads();
    float h = b1[t];
#pragma unroll 8
    for (int kk = 0; kk < DIM; ++kk) h = fmaf(ar[kk], W1[kk * 128 + t], h);
    float val = fmaxf(h, 0.0f) * W2[t];
#pragma unroll
    for (int off = 32; off > 0; off >>= 1) val += __shfl_xor(val, off);
    if ((t & 63) == 0) red[t >> 6] = val;
    __syncthreads();
    if (t == 0) logits[row] = red[0] + red[1] + b2[0];
}

// ---------------- softmax over 8192 logits -> log2(b + 1e-20) ----------------
__global__ __launch_bounds__(1024) void softmax_logb(const float* __restrict__ logits,
                                                     float* __restrict__ logb2) {
    __shared__ float redm[16], reds[16];
    const int t = threadIdx.x;
    float l[8];
    float m = -INFINITY;
#pragma unroll
    for (int i = 0; i < 8; ++i) { l[i] = logits[i * 1024 + t]; m = fmaxf(m, l[i]); }
#pragma unroll
    for (int off = 32; off > 0; off >>= 1) m = fmaxf(m, __shfl_xor(m, off));
    if ((t & 63) == 0) redm[t >> 6] = m;
    __syncthreads();
    if (t < 64) {
        float v = (t < 16) ? redm[t] : -INFINITY;
#pragma unroll
        for (int off = 8; off > 0; off >>= 1) v = fmaxf(v, __shfl_xor(v, off));
        if (t == 0) redm[0] = v;
    }
    __syncthreads();
    m = redm[0];
    float s = 0.0f;
#pragma unroll
    for (int i = 0; i < 8; ++i) s += __expf(l[i] - m);
#pragma unroll
    for (int off = 32; off > 0; off >>= 1) s += __shfl_xor(s, off);
    if ((t & 63) == 0) reds[t >> 6] = s;
    __syncthreads();
    if (t < 64) {
        float v = (t < 16) ? reds[t] : 0.0f;
#pragma unroll
        for (int off = 8; off > 0; off >>= 1) v += __shfl_xor(v, off);
        if (t == 0) reds[0] = v;
    }
    __syncthreads();
    s = reds[0];
    float invs = 1.0f / s;
#pragma unroll
    for (int i = 0; i < 8; ++i)
        logb2[i * 1024 + t] = log2f(__expf(l[i] - m) * invs + 1e-20f);
}

// ---------------- fused iteration: DMA staging + 2 blocks/CU overlap ----------------
__global__ __launch_bounds__(512, 4) void iter_fused(const float* __restrict__ S,
                                                     const float* __restrict__ g,
                                                     const float* __restrict__ logb2,
                                                     float* __restrict__ f,
                                                     float* __restrict__ pm) {
    __shared__ float buf[RSC][NR];      // 64 KB staging (single buffer)
    __shared__ float redm[8], reds[8];
    const int t = threadIdx.x;
    const int wv = t >> 6, lane = t & 63;
    const int chunk = blockIdx.x;
    const int r0 = chunk * CROWS;
    const int rw = wv >> 2;             // row (0..1) within sub-chunk
    const int qt = wv & 3;              // quarter of the row this wave handles
    const int qbase = qt * 2048;
    const int loff = lane * 4;

    // preload this wave's g quarter (constant within one launch): 8 float4
    float4 greg[8];
#pragma unroll
    for (int it = 0; it < 8; ++it)
        greg[it] = *(const float4*)(g + qbase + it * 256 + loff);

    // column accumulators: thread t owns cols {j*2048 + t*4 + c}
    float cm[4][4], cs[4][4];
#pragma unroll
    for (int j = 0; j < 4; ++j)
#pragma unroll
        for (int c = 0; c < 4; ++c) { cm[j][c] = -INFINITY; cs[j][c] = 0.0f; }

    // prologue: DMA sub-chunk 0
    {
        const float* Sr = S + (size_t)(r0 + rw) * NR + qbase;
        float* ld = &buf[rw][qbase];
#pragma unroll
        for (int it = 0; it < 8; ++it)
#if __has_builtin(__builtin_amdgcn_global_load_lds)
            gl2lds16(Sr + it * 256 + loff, ld + it * 256);
#else
            gl2lds16(Sr + it * 256 + loff, ld + it * 256 + loff);
#endif
    }

    for (int sc = 0; sc < NSUB; ++sc) {
        wait_vm0();   // own DMA(sc) (and greg/f stragglers) complete
        // ---- phase 1: row-LSE over this wave's quarter (LDS + g regs) ----
        float m = -INFINITY, s = 0.0f;
#pragma unroll
        for (int it = 0; it < 8; ++it) {
            float4 v = *(const float4*)&buf[rw][qbase + it * 256 + loff];
            float4 gv = greg[it];
            lse_upd4(m, s, v.x + gv.x, v.y + gv.y, v.z + gv.z, v.w + gv.w);
        }
#pragma unroll
        for (int off = 32; off > 0; off >>= 1) {
            float mo = __shfl_xor(m, off);
            float so = __shfl_xor(s, off);
            lse_comb2(m, s, mo, so);
        }
        if (lane == 0) { redm[wv] = m; reds[wv] = s; }
        bar_lgkm();   // barrier A: all DMA(sc) complete block-wide; red visible

        // ---- all threads: combine 4 quarter partials per row -> f0, f1 ----
        float fr[RSC];
#pragma unroll
        for (int r = 0; r < RSC; ++r) {
            float mm = redm[r * 4 + 0], ss = reds[r * 4 + 0];
            lse_comb2(mm, ss, redm[r * 4 + 1], reds[r * 4 + 1]);
            lse_comb2(mm, ss, redm[r * 4 + 2], reds[r * 4 + 2]);
            lse_comb2(mm, ss, redm[r * 4 + 3], reds[r * 4 + 3]);
            fr[r] = logb2[r0 + sc * RSC + r] - (mm + flog2(ss));
        }
        if (t < RSC) f[r0 + sc * RSC + t] = fr[t];

        // ---- phase 2: column partial-LSE over the 2 staged rows (LDS) ----
#pragma unroll
        for (int j = 0; j < 4; ++j) {
            const int c = j * 2048 + t * 4;
            float4 a = *(const float4*)&buf[0][c];
            float4 bb = *(const float4*)&buf[1][c];
            lse_upd2(cm[j][0], cs[j][0], a.x + fr[0], bb.x + fr[1]);
            lse_upd2(cm[j][1], cs[j][1], a.y + fr[0], bb.y + fr[1]);
            lse_upd2(cm[j][2], cs[j][2], a.z + fr[0], bb.z + fr[1]);
            lse_upd2(cm[j][3], cs[j][3], a.w + fr[0], bb.w + fr[1]);
        }
        bar_lgkm();   // barrier B: every wave done reading buf

        // ---- issue DMA for sub-chunk sc+1 (safe: all reads of buf finished) ----
        if (sc + 1 < NSUB) {
            const float* Sn = S + (size_t)(r0 + (sc + 1) * RSC + rw) * NR + qbase;
            float* ld = &buf[rw][qbase];
#pragma unroll
            for (int it = 0; it < 8; ++it)
#if __has_builtin(__builtin_amdgcn_global_load_lds)
                gl2lds16(Sn + it * 256 + loff, ld + it * 256);
#else
                gl2lds16(Sn + it * 256 + loff, ld + it * 256 + loff);
#endif
        }
    }
    // write column partials for this chunk as a single float L = m + log2(s)
#pragma unroll
    for (int j = 0; j < 4; ++j) {
        float4 L;
        L.x = cm[j][0] + flog2(cs[j][0]);
        L.y = cm[j][1] + flog2(cs[j][1]);
        L.z = cm[j][2] + flog2(cs[j][2]);
        L.w = cm[j][3] + flog2(cs[j][3]);
        *(float4*)&pm[(size_t)chunk * NR + j * 2048 + t * 4] = L;
    }
}

// ---------------- combine partials -> g (256 blocks, two-level LSE) ----------------
__global__ __launch_bounds__(256) void col_combine(const float* __restrict__ pm,
                                                   float* __restrict__ g,
                                                   float log_a2) {
    __shared__ float Lsh[8][32];
    const int cl = threadIdx.x & 31;       // column within block
    const int gp = threadIdx.x >> 5;       // chunk group (0..7), 64 chunks each
    const int col = blockIdx.x * 32 + cl;
    float m = -INFINITY, s = 0.0f;
#pragma unroll
    for (int ch = gp * 64; ch < gp * 64 + 64; ch += 4) {
        float l0 = pm[(size_t)(ch + 0) * NR + col];
        float l1 = pm[(size_t)(ch + 1) * NR + col];
        float l2 = pm[(size_t)(ch + 2) * NR + col];
        float l3 = pm[(size_t)(ch + 3) * NR + col];
        lse_upd4(m, s, l0, l1, l2, l3);
    }
    Lsh[gp][cl] = m + flog2(s);
    __syncthreads();
    if (gp == 0) {
        float mm = -INFINITY, ss = 0.0f;
        lse_upd4(mm, ss, Lsh[0][cl], Lsh[1][cl], Lsh[2][cl], Lsh[3][cl]);
        lse_upd4(mm, ss, Lsh[4][cl], Lsh[5][cl], Lsh[6][cl], Lsh[7][cl]);
        g[col] = log_a2 - (mm + flog2(ss));
    }
}

// ---------------- T = exp2(f + S + g), in place; global sum == 1 analytically ------
// note: no __restrict__ on S/out — they alias (in-place)
__global__ __launch_bounds__(256) void write_pass(const float* S,
                                                  const float* __restrict__ f,
                                                  const float* __restrict__ g,
                                                  float* out) {
    const int wv = threadIdx.x >> 6, lane = threadIdx.x & 63;
    const int row = blockIdx.x * 4 + wv;
    const float fi = f[row];
    const float4* Sr = (const float4*)(S + (size_t)row * NR);
    const float4* gr = (const float4*)g;
    float4* Or = (float4*)(out + (size_t)row * NR);
#pragma unroll 4
    for (int it = 0; it < NR / 256; ++it) {
        const int idx = it * 64 + lane;
        float4 sv = Sr[idx];
        float4 gv = gr[idx];
        float4 o;
        o.x = fexp2(fi + sv.x + gv.x);
        o.y = fexp2(fi + sv.y + gv.y);
        o.z = fexp2(fi + sv.z + gv.z);
        o.w = fexp2(fi + sv.w + gv.w);
        Or[idx] = o;
    }
}

extern "C" void kernel_launch(void* const* d_in, const int* in_sizes, int n_in,
                              void* d_out, int out_size, void* d_ws, size_t ws_size,
                              hipStream_t stream) {
    (void)in_sizes; (void)n_in; (void)out_size; (void)ws_size;
    const float* A  = (const float*)d_in[0];
    const float* Tk = (const float*)d_in[1];
    const float* Wq = (const float*)d_in[2];
    const float* bq = (const float*)d_in[3];
    const float* Wk = (const float*)d_in[4];
    const float* bk = (const float*)d_in[5];
    const float* W1 = (const float*)d_in[6];
    const float* b1 = (const float*)d_in[7];
    const float* W2 = (const float*)d_in[8];
    const float* b2 = (const float*)d_in[9];
    float* S  = (float*)d_out;           // 8192x8192 base-2 log_K lives in d_out
    float* ws = (float*)d_ws;
    float* qn     = ws; ws += NR;
    float* kn     = ws; ws += NR;
    float* logb2  = ws; ws += NR;
    float* logits = ws; ws += NR;
    float* f      = ws; ws += NR;
    float* g      = ws; ws += NR;
    float* pm     = ws; ws += (size_t)NBLK * NR;   // 16 MB
    float* q      = ws; ws += (size_t)NR * DIM;    // 8 MB
    float* k      = ws; ws += (size_t)NR * DIM;    // 8 MB
    // bf16 split arrays overlay pm (16.78 MB == 4 x NR*DIM ushorts): they are
    // dead once dist_mfma finishes, before the first iter_fused writes pm.
    ushort_t* qh = (ushort_t*)pm;
    ushort_t* ql = qh + (size_t)NR * DIM;
    ushort_t* kh = ql + (size_t)NR * DIM;
    ushort_t* kl = kh + (size_t)NR * DIM;

    const float log_a2 = -13.0f; // log2(1/8192 + 1e-20)

    init_zero<<<32, 256, 0, stream>>>(g);
    gemm_qk<<<dim3(128, 4), 256, 0, stream>>>(A, Wq, bq, q);
    gemm_qk<<<dim3(128, 4), 256, 0, stream>>>(Tk, Wk, bk, k);
    row_norm<<<NR, 64, 0, stream>>>(q, qn);
    row_norm<<<NR, 64, 0, stream>>>(k, kn);
    split_bf16<<<NR * DIM / 1024, 256, 0, stream>>>(q, qh, ql);
    split_bf16<<<NR * DIM / 1024, 256, 0, stream>>>(k, kh, kl);
    mlp_logits<<<NR, 128, 0, stream>>>(A, W1, b1, W2, b2, logits);
    softmax_logb<<<1, 1024, 0, stream>>>(logits, logb2);
    dist_mfma<<<dim3(64, 64), 256, 0, stream>>>(qh, ql, kh, kl, qn, kn, S);
    for (int it = 0; it < 50; ++it) {
        iter_fused<<<NBLK, 512, 0, stream>>>(S, g, logb2, f, pm);
        col_combine<<<NR / 32, 256, 0, stream>>>(pm, g, log_a2);
    }
    write_pass<<<NR / 4, 256, 0, stream>>>(S, f, g, S);
}